// Round 1
// baseline (798.581 us; speedup 1.0000x reference)
//
#include <hip/hip_runtime.h>
#include <cstdint>

typedef unsigned short u16;
typedef __attribute__((ext_vector_type(8))) __bf16 bf16x8;
typedef __attribute__((ext_vector_type(4))) float f32x4;

__device__ __forceinline__ u16 f2bf(float f) {
  unsigned int u = __builtin_bit_cast(unsigned int, f);
  unsigned int r = (u + 0x7fffu + ((u >> 16) & 1u)) >> 16;
  return (u16)r;
}

// XOR-swizzle helpers: 16B-chunk position within a 128B row XORed with (row&7).
// Keeps 8-element (16B) groups contiguous so b128 LDS ops still work.
__device__ __forceinline__ int swz64i(int row, int col) {   // 64 u16 cols per row
  return row * 64 + (((col & 0x38) ^ ((row & 7) << 3)) | (col & 7));
}
__device__ __forceinline__ int swz128i(int row, int col) {  // 128 u16 cols per row
  return row * 128 + (((col & 0x78) ^ ((row & 7) << 3)) | (col & 7));
}

// ---------------- fp32 -> bf16 conversion ----------------
__global__ __launch_bounds__(256) void cvt_bf16_kernel(const float* __restrict__ in,
                                                       u16* __restrict__ out, long n4) {
  long i = (long)blockIdx.x * 256 + threadIdx.x;
  long stride = (long)gridDim.x * 256;
  const float4* in4 = (const float4*)in;
  uint2* out2 = (uint2*)out;
  for (long k = i; k < n4; k += stride) {
    float4 v = in4[k];
    uint2 o;
    o.x = (unsigned int)f2bf(v.x) | ((unsigned int)f2bf(v.y) << 16);
    o.y = (unsigned int)f2bf(v.z) | ((unsigned int)f2bf(v.w) << 16);
    out2[k] = o;
  }
}

// ---------------- bf16 GEMM, C[M][N] = A[M][K] * B[N][K]^T (fp32 out) ----------------
// 128x128 tile, BK=32, 4 waves each 64x64 (4x4 fragments of 16x16x32 MFMA).
__global__ __launch_bounds__(256) void gemm_bt(const u16* __restrict__ A,
                                               const u16* __restrict__ B,
                                               float* __restrict__ C,
                                               int M, int N, int K) {
  __shared__ __align__(16) u16 As[128 * 32];
  __shared__ __align__(16) u16 Bs[128 * 32];
  const int tid = threadIdx.x;
  const int lane = tid & 63, wave = tid >> 6;
  const int l15 = lane & 15, l4 = lane >> 4;
  const long arow = (long)blockIdx.y * 128, brow = (long)blockIdx.x * 128;
  const int wm = (wave >> 1) * 64, wn = (wave & 1) * 64;
  f32x4 acc[4][4] = {};
  for (int kk = 0; kk < K; kk += 32) {
    #pragma unroll
    for (int c = 0; c < 2; ++c) {
      int i = tid + c * 256;          // 512 chunks of 16B
      int r = i >> 2, k8 = (i & 3) * 8;
      *(uint4*)&As[r * 32 + k8] = *(const uint4*)&A[(arow + r) * K + kk + k8];
      *(uint4*)&Bs[r * 32 + k8] = *(const uint4*)&B[(brow + r) * K + kk + k8];
    }
    __syncthreads();
    bf16x8 af[4], bfr[4];
    #pragma unroll
    for (int x = 0; x < 4; ++x) {
      af[x]  = *(const bf16x8*)&As[(wm + x * 16 + l15) * 32 + l4 * 8];
      bfr[x] = *(const bf16x8*)&Bs[(wn + x * 16 + l15) * 32 + l4 * 8];
    }
    #pragma unroll
    for (int mi = 0; mi < 4; ++mi)
      #pragma unroll
      for (int ni = 0; ni < 4; ++ni)
        acc[mi][ni] = __builtin_amdgcn_mfma_f32_16x16x32_bf16(af[mi], bfr[ni], acc[mi][ni], 0, 0, 0);
    __syncthreads();
  }
  #pragma unroll
  for (int mi = 0; mi < 4; ++mi)
    #pragma unroll
    for (int ni = 0; ni < 4; ++ni)
      #pragma unroll
      for (int j = 0; j < 4; ++j) {
        long r = arow + wm + mi * 16 + l4 * 4 + j;
        long c = brow + wn + ni * 16 + l15;
        C[r * N + c] = acc[mi][ni][j];
      }
}

// ---------------- fused per-head LayerNorm + RoPE (+ v passthrough convert) ----------------
// grid = (96, T): hh in [0,32) -> q (LN+RoPE, pre-scaled by 1/sqrt(D)),
// [32,64) -> k (LN+RoPE), [64,96) -> v (convert only). 1 wave per row; lane
// holds elements (i, i+64), exactly the RoPE pair.
__global__ __launch_bounds__(64) void ln_rope_kernel(
    const float* __restrict__ qkv, const int* __restrict__ pos,
    const float* __restrict__ qw, const float* __restrict__ qb2,
    const float* __restrict__ kw, const float* __restrict__ kb2,
    u16* __restrict__ qo, u16* __restrict__ ko, u16* __restrict__ vo, int T) {
  const int hh = blockIdx.x;
  const int t = blockIdx.y;
  const int lane = threadIdx.x;
  const float* src = qkv + (size_t)t * 12288 + hh * 128;
  float x1 = src[lane], x2 = src[lane + 64];
  if (hh >= 64) {
    u16* dst = vo + ((size_t)(hh - 64) * T + t) * 128;
    dst[lane] = f2bf(x1); dst[lane + 64] = f2bf(x2);
    return;
  }
  float s = x1 + x2;
  #pragma unroll
  for (int off = 32; off; off >>= 1) s += __shfl_xor(s, off);
  float mu = s * (1.0f / 128.0f);
  float d1 = x1 - mu, d2 = x2 - mu;
  float vs = d1 * d1 + d2 * d2;
  #pragma unroll
  for (int off = 32; off; off >>= 1) vs += __shfl_xor(vs, off);
  float rstd = rsqrtf(vs * (1.0f / 128.0f) + 1e-5f);
  bool isq = hh < 32;
  int hl = isq ? hh : hh - 32;
  const float* w = (isq ? qw : kw) + hl * 128;
  const float* b = (isq ? qb2 : kb2) + hl * 128;
  float y1 = d1 * rstd * w[lane] + b[lane];
  float y2 = d2 * rstd * w[lane + 64] + b[lane + 64];
  float p = (float)pos[t];
  // inv_freq = 10000^(-lane/64) = 2^(-lane*log2(10000)/64)
  float invf = exp2f((float)lane * (-13.287712379549449f / 64.0f));
  float fr = p * invf;
  float sn, cs;
  sincosf(fr, &sn, &cs);   // precise version: args up to ~2047 rad
  float o1 = y1 * cs - y2 * sn;
  float o2 = y2 * cs + y1 * sn;
  if (isq) {
    const float sc = 0.08838834764831845f;   // 1/sqrt(128), folded into q
    o1 *= sc; o2 *= sc;
    u16* dst = qo + ((size_t)hl * T + t) * 128;
    dst[lane] = f2bf(o1); dst[lane + 64] = f2bf(o2);
  } else {
    u16* dst = ko + ((size_t)hl * T + t) * 128;
    dst[lane] = f2bf(o1); dst[lane + 64] = f2bf(o2);
  }
}

// ---------------- flash attention (causal), bf16 MFMA, online softmax ----------------
// Block: 4 waves, 128 q-rows (32/wave). KV tiles of 64. Q/K/V in [h][T][D] bf16.
// Output written as attn[t][h*128+d] bf16 for the out-proj GEMM.
__global__ __launch_bounds__(256) void flash_kernel(
    const u16* __restrict__ qb, const u16* __restrict__ kb,
    const u16* __restrict__ vb, u16* __restrict__ attn, int T) {
  __shared__ __align__(16) u16 Ks[64 * 128];    // K tile, row-major [kv][d], swizzled
  __shared__ __align__(16) u16 Vt[128 * 64];    // V tile transposed [d][kv], swizzled
  __shared__ __align__(16) u16 Ps[4][32 * 64];  // per-wave P buffer, swizzled
  const int tid = threadIdx.x;
  const int lane = tid & 63, wave = tid >> 6;
  const int l15 = lane & 15, l4 = lane >> 4;
  const int h = blockIdx.y;
  const int qbase = blockIdx.x * 128;
  const int qrow0 = qbase + wave * 32;
  const u16* Q  = qb + (size_t)h * T * 128;
  const u16* Kp = kb + (size_t)h * T * 128;
  const u16* Vp = vb + (size_t)h * T * 128;

  bf16x8 qf[2][4];
  #pragma unroll
  for (int mi = 0; mi < 2; ++mi)
    #pragma unroll
    for (int kc = 0; kc < 4; ++kc)
      qf[mi][kc] = *(const bf16x8*)&Q[(size_t)(qrow0 + mi * 16 + l15) * 128 + kc * 32 + l4 * 8];

  float m_st[2][4], l_st[2][4];
  f32x4 o[2][8] = {};
  #pragma unroll
  for (int mi = 0; mi < 2; ++mi)
    #pragma unroll
    for (int j = 0; j < 4; ++j) { m_st[mi][j] = -1e30f; l_st[mi][j] = 0.0f; }

  const int ntile = (qbase + 128) / 64;
  for (int kt = 0; kt < ntile; ++kt) {
    const int kbase = kt * 64;
    #pragma unroll
    for (int c = 0; c < 4; ++c) {
      int i = tid + c * 256;
      {  // K tile: coalesced rows, 16 lanes cover one 256B row
        int r = i >> 4, d8 = (i & 15) * 8;
        *(uint4*)&Ks[swz128i(r, d8)] = *(const uint4*)&Kp[(size_t)(kbase + r) * 128 + d8];
      }
      {  // V tile transposed: lane-per-row so LDS scalar writes are conflict-free
        int r = i & 63, d8 = (i >> 6) * 8;
        uint4 v = *(const uint4*)&Vp[(size_t)(kbase + r) * 128 + d8];
        u16* pv = (u16*)&v;
        #pragma unroll
        for (int j = 0; j < 8; ++j) Vt[swz64i(d8 + j, r)] = pv[j];
      }
    }
    __syncthreads();
    if (kbase <= qrow0 + 31) {   // wave has at least one unmasked column in this tile
      f32x4 s[2][4] = {};
      #pragma unroll
      for (int kc = 0; kc < 4; ++kc)
        #pragma unroll
        for (int nj = 0; nj < 4; ++nj) {
          bf16x8 kf = *(const bf16x8*)&Ks[swz128i(nj * 16 + l15, kc * 32 + l4 * 8)];
          #pragma unroll
          for (int mi = 0; mi < 2; ++mi)
            s[mi][nj] = __builtin_amdgcn_mfma_f32_16x16x32_bf16(qf[mi][kc], kf, s[mi][nj], 0, 0, 0);
        }
      if (kbase + 63 > qrow0) {  // diagonal tile: apply causal mask
        #pragma unroll
        for (int mi = 0; mi < 2; ++mi)
          #pragma unroll
          for (int nj = 0; nj < 4; ++nj)
            #pragma unroll
            for (int j = 0; j < 4; ++j) {
              int r = qrow0 + mi * 16 + l4 * 4 + j;
              int cc = kbase + nj * 16 + l15;
              if (cc > r) s[mi][nj][j] = -1e30f;
            }
      }
      #pragma unroll
      for (int mi = 0; mi < 2; ++mi) {
        float mx[4], sum[4], scl[4];
        #pragma unroll
        for (int j = 0; j < 4; ++j) {
          float v = fmaxf(fmaxf(s[mi][0][j], s[mi][1][j]), fmaxf(s[mi][2][j], s[mi][3][j]));
          #pragma unroll
          for (int off = 1; off < 16; off <<= 1) v = fmaxf(v, __shfl_xor(v, off));
          float mn = fmaxf(m_st[mi][j], v);
          scl[j] = __expf(m_st[mi][j] - mn);
          m_st[mi][j] = mn;
          mx[j] = mn;
          sum[j] = 0.0f;
        }
        #pragma unroll
        for (int nj = 0; nj < 4; ++nj)
          #pragma unroll
          for (int j = 0; j < 4; ++j) {
            float p = __expf(s[mi][nj][j] - mx[j]);
            s[mi][nj][j] = p;
            sum[j] += p;
          }
        #pragma unroll
        for (int j = 0; j < 4; ++j) {
          #pragma unroll
          for (int off = 1; off < 16; off <<= 1) sum[j] += __shfl_xor(sum[j], off);
          l_st[mi][j] = l_st[mi][j] * scl[j] + sum[j];
        }
        #pragma unroll
        for (int nf = 0; nf < 8; ++nf)
          #pragma unroll
          for (int j = 0; j < 4; ++j) o[mi][nf][j] *= scl[j];
        // P: C-layout regs -> swizzled LDS (read back below in A-layout)
        #pragma unroll
        for (int nj = 0; nj < 4; ++nj)
          #pragma unroll
          for (int j = 0; j < 4; ++j)
            Ps[wave][swz64i(mi * 16 + l4 * 4 + j, nj * 16 + l15)] = f2bf(s[mi][nj][j]);
      }
      asm volatile("s_waitcnt lgkmcnt(0)" ::: "memory");  // P writes -> P reads (cross-lane)
      __builtin_amdgcn_sched_barrier(0);
      #pragma unroll
      for (int mi = 0; mi < 2; ++mi)
        #pragma unroll
        for (int kc = 0; kc < 2; ++kc) {
          bf16x8 pf = *(const bf16x8*)&Ps[wave][swz64i(mi * 16 + l15, kc * 32 + l4 * 8)];
          #pragma unroll
          for (int nf = 0; nf < 8; ++nf) {
            bf16x8 vf = *(const bf16x8*)&Vt[swz64i(nf * 16 + l15, kc * 32 + l4 * 8)];
            o[mi][nf] = __builtin_amdgcn_mfma_f32_16x16x32_bf16(pf, vf, o[mi][nf], 0, 0, 0);
          }
        }
    }
    __syncthreads();
  }
  #pragma unroll
  for (int mi = 0; mi < 2; ++mi)
    #pragma unroll
    for (int nf = 0; nf < 8; ++nf)
      #pragma unroll
      for (int j = 0; j < 4; ++j) {
        int r = qrow0 + mi * 16 + l4 * 4 + j;
        int cc = h * 128 + nf * 16 + l15;
        attn[(size_t)r * 4096 + cc] = f2bf(o[mi][nf][j] / l_st[mi][j]);
      }
}

// ---------------- launch ----------------
extern "C" void kernel_launch(void* const* d_in, const int* in_sizes, int n_in,
                              void* d_out, int out_size, void* d_ws, size_t ws_size,
                              hipStream_t stream) {
  const int* positions = (const int*)d_in[0];
  const float* hidden  = (const float*)d_in[1];
  const float* w_qkv   = (const float*)d_in[2];
  const float* w_o     = (const float*)d_in[3];
  const float* qnw     = (const float*)d_in[4];
  const float* qnb     = (const float*)d_in[5];
  const float* knw     = (const float*)d_in[6];
  const float* knb     = (const float*)d_in[7];
  float* out = (float*)d_out;

  const int T = in_sizes[0];           // 2048
  const int HID = 4096, NQKV = 12288, H = 32;

  // ws layout (218.1 MB total):
  //   [0]                hidden_bf16   : T*HID u16
  //   [A]                w-region      : NQKV*HID u16 — first holds w_qkv bf16;
  //                      after QKV GEMM it is recycled as q|k|v|attn|w_o (exact fit)
  //   [B]                qkv fp32      : T*NQKV f32
  char* ws = (char*)d_ws;
  u16* hid_bf  = (u16*)ws;
  u16* wreg    = (u16*)(ws + (size_t)T * HID * 2);
  float* qkv_f = (float*)(ws + (size_t)T * HID * 2 + (size_t)NQKV * HID * 2);

  u16* q_bf  = wreg;                                 // [H][T][128]
  u16* k_bf  = q_bf + (size_t)H * T * 128;           // [H][T][128]
  u16* v_bf  = k_bf + (size_t)H * T * 128;           // [H][T][128]
  u16* at_bf = v_bf + (size_t)H * T * 128;           // [T][H*128]
  u16* wo_bf = at_bf + (size_t)T * 4096;             // [4096][4096]

  // 1-2. convert hidden and w_qkv to bf16
  cvt_bf16_kernel<<<2048, 256, 0, stream>>>(hidden, hid_bf, (long)T * HID / 4);
  cvt_bf16_kernel<<<4096, 256, 0, stream>>>(w_qkv, wreg, (long)NQKV * HID / 4);
  // 3. QKV GEMM: qkv[T][12288] = hidden * w_qkv^T
  gemm_bt<<<dim3(NQKV / 128, T / 128), 256, 0, stream>>>(hid_bf, wreg, qkv_f, T, NQKV, HID);
  // 4. per-head LN + RoPE (+ v convert), writes head-major bf16 q/k/v
  ln_rope_kernel<<<dim3(96, T), 64, 0, stream>>>(qkv_f, positions, qnw, qnb, knw, knb,
                                                 q_bf, k_bf, v_bf, T);
  // 5. convert w_o to bf16 (region freed by step 3's completion)
  cvt_bf16_kernel<<<2048, 256, 0, stream>>>(w_o, wo_bf, (long)HID * HID / 4);
  // 6. causal flash attention -> attn[T][4096] bf16
  flash_kernel<<<dim3(T / 128, H), 256, 0, stream>>>(q_bf, k_bf, v_bf, at_bf, T);
  // 7. out projection: out[T][4096] = attn * w_o^T (fp32 out)
  gemm_bt<<<dim3(HID / 128, T / 128), 256, 0, stream>>>(at_bf, wo_bf, out, T, HID, HID);
}

// Round 2
// 778.867 us; speedup vs baseline: 1.0253x; 1.0253x over previous
//
#include <hip/hip_runtime.h>
#include <cstdint>

typedef unsigned short u16;
typedef __attribute__((ext_vector_type(8))) __bf16 bf16x8;
typedef __attribute__((ext_vector_type(4))) float f32x4;

__device__ __forceinline__ u16 f2bf(float f) {
  unsigned int u = __builtin_bit_cast(unsigned int, f);
  unsigned int r = (u + 0x7fffu + ((u >> 16) & 1u)) >> 16;
  return (u16)r;
}

// async global->LDS, 16B per lane. LDS dest must be linear in lane (wave base + lane*16).
__device__ __forceinline__ void gload16(const u16* g, u16* l) {
  __builtin_amdgcn_global_load_lds((const __attribute__((address_space(1))) void*)g,
                                   (__attribute__((address_space(3))) void*)l, 16, 0, 0);
}

// XOR-swizzle helpers: 16B-chunk position within a 128B row XORed with (row&7).
__device__ __forceinline__ int swz64i(int row, int col) {   // 64 u16 cols per row
  return row * 64 + (((col & 0x38) ^ ((row & 7) << 3)) | (col & 7));
}
__device__ __forceinline__ int swz128i(int row, int col) {  // 128 u16 cols per row
  return row * 128 + (((col & 0x78) ^ ((row & 7) << 3)) | (col & 7));
}

// ---------------- fp32 -> bf16 conversion ----------------
__global__ __launch_bounds__(256) void cvt_bf16_kernel(const float* __restrict__ in,
                                                       u16* __restrict__ out, long n4) {
  long i = (long)blockIdx.x * 256 + threadIdx.x;
  long stride = (long)gridDim.x * 256;
  const float4* in4 = (const float4*)in;
  uint2* out2 = (uint2*)out;
  for (long k = i; k < n4; k += stride) {
    float4 v = in4[k];
    uint2 o;
    o.x = (unsigned int)f2bf(v.x) | ((unsigned int)f2bf(v.y) << 16);
    o.y = (unsigned int)f2bf(v.z) | ((unsigned int)f2bf(v.w) << 16);
    out2[k] = o;
  }
}

// ---------------- bf16 GEMM, C[M][N] = A[M][K] * B[N][K]^T (fp32 out) ----------------
// m97 structure: 128x128 tile, BK=32, 4 waves each 64x64, global_load_lds(16B) staging,
// linear LDS (required by gload_lds lane-linear dest), ds_read_b128 fragments.
__global__ __launch_bounds__(256) void gemm_bt(const u16* __restrict__ A,
                                               const u16* __restrict__ B,
                                               float* __restrict__ C,
                                               int M, int N, int K) {
  __shared__ __align__(16) u16 As[128 * 32];
  __shared__ __align__(16) u16 Bs[128 * 32];
  const int tid = threadIdx.x;
  const int lane = tid & 63, wave = tid >> 6;
  const int l15 = lane & 15, l4 = lane >> 4;
  const long arow = (long)blockIdx.y * 128, brow = (long)blockIdx.x * 128;
  const int wm = (wave >> 1) * 64, wn = (wave & 1) * 64;
  // staging addresses: wave covers rows [wave*32, wave*32+32) of both tiles,
  // as 2 chunks of 16 rows; lane covers row chunk0+lane/4, 16B piece lane%4.
  const int r0 = wave * 32;
  const int rl = lane >> 2, k8 = (lane & 3) * 8;
  const u16* ga0 = &A[(arow + r0 + rl) * (long)K + k8];
  const u16* ga1 = &A[(arow + r0 + 16 + rl) * (long)K + k8];
  const u16* gb0 = &B[(brow + r0 + rl) * (long)K + k8];
  const u16* gb1 = &B[(brow + r0 + 16 + rl) * (long)K + k8];
  u16* la0 = &As[r0 * 32 + lane * 8];
  u16* la1 = &As[(r0 + 16) * 32 + lane * 8];
  u16* lb0 = &Bs[r0 * 32 + lane * 8];
  u16* lb1 = &Bs[(r0 + 16) * 32 + lane * 8];
  f32x4 acc[4][4] = {};
  for (int kk = 0; kk < K; kk += 32) {
    gload16(ga0 + kk, la0);
    gload16(ga1 + kk, la1);
    gload16(gb0 + kk, lb0);
    gload16(gb1 + kk, lb1);
    __syncthreads();
    bf16x8 af[4], bfr[4];
    #pragma unroll
    for (int x = 0; x < 4; ++x) {
      af[x]  = *(const bf16x8*)&As[(wm + x * 16 + l15) * 32 + l4 * 8];
      bfr[x] = *(const bf16x8*)&Bs[(wn + x * 16 + l15) * 32 + l4 * 8];
    }
    #pragma unroll
    for (int mi = 0; mi < 4; ++mi)
      #pragma unroll
      for (int ni = 0; ni < 4; ++ni)
        acc[mi][ni] = __builtin_amdgcn_mfma_f32_16x16x32_bf16(af[mi], bfr[ni], acc[mi][ni], 0, 0, 0);
    __syncthreads();
  }
  #pragma unroll
  for (int mi = 0; mi < 4; ++mi)
    #pragma unroll
    for (int ni = 0; ni < 4; ++ni)
      #pragma unroll
      for (int j = 0; j < 4; ++j) {
        long r = arow + wm + mi * 16 + l4 * 4 + j;
        long c = brow + wn + ni * 16 + l15;
        C[r * N + c] = acc[mi][ni][j];
      }
}

// ---------------- fused per-head LayerNorm + RoPE (+ v passthrough convert) ----------------
__global__ __launch_bounds__(64) void ln_rope_kernel(
    const float* __restrict__ qkv, const int* __restrict__ pos,
    const float* __restrict__ qw, const float* __restrict__ qb2,
    const float* __restrict__ kw, const float* __restrict__ kb2,
    u16* __restrict__ qo, u16* __restrict__ ko, u16* __restrict__ vo, int T) {
  const int hh = blockIdx.x;
  const int t = blockIdx.y;
  const int lane = threadIdx.x;
  const float* src = qkv + (size_t)t * 12288 + hh * 128;
  float x1 = src[lane], x2 = src[lane + 64];
  if (hh >= 64) {
    u16* dst = vo + ((size_t)(hh - 64) * T + t) * 128;
    dst[lane] = f2bf(x1); dst[lane + 64] = f2bf(x2);
    return;
  }
  float s = x1 + x2;
  #pragma unroll
  for (int off = 32; off; off >>= 1) s += __shfl_xor(s, off);
  float mu = s * (1.0f / 128.0f);
  float d1 = x1 - mu, d2 = x2 - mu;
  float vs = d1 * d1 + d2 * d2;
  #pragma unroll
  for (int off = 32; off; off >>= 1) vs += __shfl_xor(vs, off);
  float rstd = rsqrtf(vs * (1.0f / 128.0f) + 1e-5f);
  bool isq = hh < 32;
  int hl = isq ? hh : hh - 32;
  const float* w = (isq ? qw : kw) + hl * 128;
  const float* b = (isq ? qb2 : kb2) + hl * 128;
  float y1 = d1 * rstd * w[lane] + b[lane];
  float y2 = d2 * rstd * w[lane + 64] + b[lane + 64];
  float p = (float)pos[t];
  float invf = exp2f((float)lane * (-13.287712379549449f / 64.0f));
  float fr = p * invf;
  float sn, cs;
  sincosf(fr, &sn, &cs);
  float o1 = y1 * cs - y2 * sn;
  float o2 = y2 * cs + y1 * sn;
  if (isq) {
    const float sc = 0.08838834764831845f;   // 1/sqrt(128) folded into q
    o1 *= sc; o2 *= sc;
    u16* dst = qo + ((size_t)hl * T + t) * 128;
    dst[lane] = f2bf(o1); dst[lane + 64] = f2bf(o2);
  } else {
    u16* dst = ko + ((size_t)hl * T + t) * 128;
    dst[lane] = f2bf(o1); dst[lane + 64] = f2bf(o2);
  }
}

// ---------------- flash attention (causal), bf16 MFMA, online softmax ----------------
__global__ __launch_bounds__(256) void flash_kernel(
    const u16* __restrict__ qb, const u16* __restrict__ kb,
    const u16* __restrict__ vb, u16* __restrict__ attn, int T) {
  __shared__ __align__(16) u16 Ks[64 * 128];    // K tile, row-major [kv][d], swizzled
  __shared__ __align__(16) u16 Vt[128 * 64];    // V tile transposed [d][kv], swizzled
  __shared__ __align__(16) u16 Ps[4][32 * 64];  // per-wave P buffer, swizzled
  const int tid = threadIdx.x;
  const int lane = tid & 63, wave = tid >> 6;
  const int l15 = lane & 15, l4 = lane >> 4;
  const int h = blockIdx.y;
  const int qbase = blockIdx.x * 128;
  const int qrow0 = qbase + wave * 32;
  const u16* Q  = qb + (size_t)h * T * 128;
  const u16* Kp = kb + (size_t)h * T * 128;
  const u16* Vp = vb + (size_t)h * T * 128;

  bf16x8 qf[2][4];
  #pragma unroll
  for (int mi = 0; mi < 2; ++mi)
    #pragma unroll
    for (int kc = 0; kc < 4; ++kc)
      qf[mi][kc] = *(const bf16x8*)&Q[(size_t)(qrow0 + mi * 16 + l15) * 128 + kc * 32 + l4 * 8];

  float m_st[2][4], l_st[2][4];
  f32x4 o[2][8] = {};
  #pragma unroll
  for (int mi = 0; mi < 2; ++mi)
    #pragma unroll
    for (int j = 0; j < 4; ++j) { m_st[mi][j] = -1e30f; l_st[mi][j] = 0.0f; }

  const int ntile = (qbase + 128) / 64;
  for (int kt = 0; kt < ntile; ++kt) {
    const int kbase = kt * 64;
    #pragma unroll
    for (int c = 0; c < 4; ++c) {
      int i = tid + c * 256;
      {  // K tile: coalesced rows, 16 lanes cover one 256B row
        int r = i >> 4, d8 = (i & 15) * 8;
        *(uint4*)&Ks[swz128i(r, d8)] = *(const uint4*)&Kp[(size_t)(kbase + r) * 128 + d8];
      }
      {  // V tile transposed
        int r = i & 63, d8 = (i >> 6) * 8;
        uint4 v = *(const uint4*)&Vp[(size_t)(kbase + r) * 128 + d8];
        u16* pv = (u16*)&v;
        #pragma unroll
        for (int j = 0; j < 8; ++j) Vt[swz64i(d8 + j, r)] = pv[j];
      }
    }
    __syncthreads();
    if (kbase <= qrow0 + 31) {
      f32x4 s[2][4] = {};
      #pragma unroll
      for (int kc = 0; kc < 4; ++kc)
        #pragma unroll
        for (int nj = 0; nj < 4; ++nj) {
          bf16x8 kf = *(const bf16x8*)&Ks[swz128i(nj * 16 + l15, kc * 32 + l4 * 8)];
          #pragma unroll
          for (int mi = 0; mi < 2; ++mi)
            s[mi][nj] = __builtin_amdgcn_mfma_f32_16x16x32_bf16(qf[mi][kc], kf, s[mi][nj], 0, 0, 0);
        }
      if (kbase + 63 > qrow0) {
        #pragma unroll
        for (int mi = 0; mi < 2; ++mi)
          #pragma unroll
          for (int nj = 0; nj < 4; ++nj)
            #pragma unroll
            for (int j = 0; j < 4; ++j) {
              int r = qrow0 + mi * 16 + l4 * 4 + j;
              int cc = kbase + nj * 16 + l15;
              if (cc > r) s[mi][nj][j] = -1e30f;
            }
      }
      #pragma unroll
      for (int mi = 0; mi < 2; ++mi) {
        float mx[4], sum[4], scl[4];
        #pragma unroll
        for (int j = 0; j < 4; ++j) {
          float v = fmaxf(fmaxf(s[mi][0][j], s[mi][1][j]), fmaxf(s[mi][2][j], s[mi][3][j]));
          #pragma unroll
          for (int off = 1; off < 16; off <<= 1) v = fmaxf(v, __shfl_xor(v, off));
          float mn = fmaxf(m_st[mi][j], v);
          scl[j] = __expf(m_st[mi][j] - mn);
          m_st[mi][j] = mn;
          mx[j] = mn;
          sum[j] = 0.0f;
        }
        #pragma unroll
        for (int nj = 0; nj < 4; ++nj)
          #pragma unroll
          for (int j = 0; j < 4; ++j) {
            float p = __expf(s[mi][nj][j] - mx[j]);
            s[mi][nj][j] = p;
            sum[j] += p;
          }
        #pragma unroll
        for (int j = 0; j < 4; ++j) {
          #pragma unroll
          for (int off = 1; off < 16; off <<= 1) sum[j] += __shfl_xor(sum[j], off);
          l_st[mi][j] = l_st[mi][j] * scl[j] + sum[j];
        }
        #pragma unroll
        for (int nf = 0; nf < 8; ++nf)
          #pragma unroll
          for (int j = 0; j < 4; ++j) o[mi][nf][j] *= scl[j];
        #pragma unroll
        for (int nj = 0; nj < 4; ++nj)
          #pragma unroll
          for (int j = 0; j < 4; ++j)
            Ps[wave][swz64i(mi * 16 + l4 * 4 + j, nj * 16 + l15)] = f2bf(s[mi][nj][j]);
      }
      asm volatile("s_waitcnt lgkmcnt(0)" ::: "memory");
      __builtin_amdgcn_sched_barrier(0);
      #pragma unroll
      for (int mi = 0; mi < 2; ++mi)
        #pragma unroll
        for (int kc = 0; kc < 2; ++kc) {
          bf16x8 pf = *(const bf16x8*)&Ps[wave][swz64i(mi * 16 + l15, kc * 32 + l4 * 8)];
          #pragma unroll
          for (int nf = 0; nf < 8; ++nf) {
            bf16x8 vf = *(const bf16x8*)&Vt[swz64i(nf * 16 + l15, kc * 32 + l4 * 8)];
            o[mi][nf] = __builtin_amdgcn_mfma_f32_16x16x32_bf16(pf, vf, o[mi][nf], 0, 0, 0);
          }
        }
    }
    __syncthreads();
  }
  #pragma unroll
  for (int mi = 0; mi < 2; ++mi)
    #pragma unroll
    for (int nf = 0; nf < 8; ++nf)
      #pragma unroll
      for (int j = 0; j < 4; ++j) {
        int r = qrow0 + mi * 16 + l4 * 4 + j;
        int cc = h * 128 + nf * 16 + l15;
        attn[(size_t)r * 4096 + cc] = f2bf(o[mi][nf][j] / l_st[mi][j]);
      }
}

// ---------------- launch ----------------
extern "C" void kernel_launch(void* const* d_in, const int* in_sizes, int n_in,
                              void* d_out, int out_size, void* d_ws, size_t ws_size,
                              hipStream_t stream) {
  const int* positions = (const int*)d_in[0];
  const float* hidden  = (const float*)d_in[1];
  const float* w_qkv   = (const float*)d_in[2];
  const float* w_o     = (const float*)d_in[3];
  const float* qnw     = (const float*)d_in[4];
  const float* qnb     = (const float*)d_in[5];
  const float* knw     = (const float*)d_in[6];
  const float* knb     = (const float*)d_in[7];
  float* out = (float*)d_out;

  const int T = in_sizes[0];           // 2048
  const int HID = 4096, NQKV = 12288, H = 32;

  char* ws = (char*)d_ws;
  u16* hid_bf  = (u16*)ws;
  u16* wreg    = (u16*)(ws + (size_t)T * HID * 2);
  float* qkv_f = (float*)(ws + (size_t)T * HID * 2 + (size_t)NQKV * HID * 2);

  u16* q_bf  = wreg;                                 // [H][T][128]
  u16* k_bf  = q_bf + (size_t)H * T * 128;           // [H][T][128]
  u16* v_bf  = k_bf + (size_t)H * T * 128;           // [H][T][128]
  u16* at_bf = v_bf + (size_t)H * T * 128;           // [T][H*128]
  u16* wo_bf = at_bf + (size_t)T * 4096;             // [4096][4096]

  cvt_bf16_kernel<<<2048, 256, 0, stream>>>(hidden, hid_bf, (long)T * HID / 4);
  cvt_bf16_kernel<<<4096, 256, 0, stream>>>(w_qkv, wreg, (long)NQKV * HID / 4);
  gemm_bt<<<dim3(NQKV / 128, T / 128), 256, 0, stream>>>(hid_bf, wreg, qkv_f, T, NQKV, HID);
  ln_rope_kernel<<<dim3(96, T), 64, 0, stream>>>(qkv_f, positions, qnw, qnb, knw, knb,
                                                 q_bf, k_bf, v_bf, T);
  cvt_bf16_kernel<<<2048, 256, 0, stream>>>(w_o, wo_bf, (long)HID * HID / 4);
  flash_kernel<<<dim3(T / 128, H), 256, 0, stream>>>(q_bf, k_bf, v_bf, at_bf, T);
  gemm_bt<<<dim3(HID / 128, T / 128), 256, 0, stream>>>(at_bf, wo_bf, out, T, HID, HID);
}

// Round 3
// 696.384 us; speedup vs baseline: 1.1468x; 1.1184x over previous
//
#include <hip/hip_runtime.h>
#include <cstdint>

typedef unsigned short u16;
typedef __attribute__((ext_vector_type(8))) __bf16 bf16x8;
typedef __attribute__((ext_vector_type(4))) float f32x4;

__device__ __forceinline__ u16 f2bf(float f) {
  unsigned int u = __builtin_bit_cast(unsigned int, f);
  unsigned int r = (u + 0x7fffu + ((u >> 16) & 1u)) >> 16;
  return (u16)r;
}

// async global->LDS, 16B per lane. LDS dest must be linear in lane (wave base + lane*16).
__device__ __forceinline__ void gload16(const u16* g, u16* l) {
  __builtin_amdgcn_global_load_lds((const __attribute__((address_space(1))) void*)g,
                                   (__attribute__((address_space(3))) void*)l, 16, 0, 0);
}

// XOR-swizzle helpers: 16B-chunk position within a 128B row XORed with (row&7).
__device__ __forceinline__ int swz64i(int row, int col) {   // 64 u16 cols per row
  return row * 64 + (((col & 0x38) ^ ((row & 7) << 3)) | (col & 7));
}
__device__ __forceinline__ int swz128i(int row, int col) {  // 128 u16 cols per row
  return row * 128 + (((col & 0x78) ^ ((row & 7) << 3)) | (col & 7));
}

// ---------------- fp32 -> bf16 conversion ----------------
__global__ __launch_bounds__(256) void cvt_bf16_kernel(const float* __restrict__ in,
                                                       u16* __restrict__ out, long n4) {
  long i = (long)blockIdx.x * 256 + threadIdx.x;
  long stride = (long)gridDim.x * 256;
  const float4* in4 = (const float4*)in;
  uint2* out2 = (uint2*)out;
  for (long k = i; k < n4; k += stride) {
    float4 v = in4[k];
    uint2 o;
    o.x = (unsigned int)f2bf(v.x) | ((unsigned int)f2bf(v.y) << 16);
    o.y = (unsigned int)f2bf(v.z) | ((unsigned int)f2bf(v.w) << 16);
    out2[k] = o;
  }
}

// ---------------- bf16 GEMM, C[M][N] = A[M][K] * B[N][K]^T (fp32 out) ----------------
// m97 structure + T1 XCD-aware block swizzle (requires gridX*gridY % 8 == 0).
__global__ __launch_bounds__(256) void gemm_bt(const u16* __restrict__ A,
                                               const u16* __restrict__ B,
                                               float* __restrict__ C,
                                               int M, int N, int K) {
  __shared__ __align__(16) u16 As[128 * 32];
  __shared__ __align__(16) u16 Bs[128 * 32];
  const int tid = threadIdx.x;
  const int lane = tid & 63, wave = tid >> 6;
  const int l15 = lane & 15, l4 = lane >> 4;
  // T1: XCD swizzle. HW dispatches linear bid x-fastest, round-robin over 8 XCDs.
  // Remap so each XCD owns a contiguous chunk of work tiles (A-panel + B-panel L2 reuse).
  const int gx = gridDim.x;
  int lin = blockIdx.y * gx + blockIdx.x;
  const int cpx = (gx * gridDim.y) >> 3;
  lin = (lin & 7) * cpx + (lin >> 3);
  const int bx = lin % gx, by = lin / gx;
  const long arow = (long)by * 128, brow = (long)bx * 128;
  const int wm = (wave >> 1) * 64, wn = (wave & 1) * 64;
  const int r0 = wave * 32;
  const int rl = lane >> 2, k8 = (lane & 3) * 8;
  const u16* ga0 = &A[(arow + r0 + rl) * (long)K + k8];
  const u16* ga1 = &A[(arow + r0 + 16 + rl) * (long)K + k8];
  const u16* gb0 = &B[(brow + r0 + rl) * (long)K + k8];
  const u16* gb1 = &B[(brow + r0 + 16 + rl) * (long)K + k8];
  u16* la0 = &As[r0 * 32 + lane * 8];
  u16* la1 = &As[(r0 + 16) * 32 + lane * 8];
  u16* lb0 = &Bs[r0 * 32 + lane * 8];
  u16* lb1 = &Bs[(r0 + 16) * 32 + lane * 8];
  f32x4 acc[4][4] = {};
  for (int kk = 0; kk < K; kk += 32) {
    gload16(ga0 + kk, la0);
    gload16(ga1 + kk, la1);
    gload16(gb0 + kk, lb0);
    gload16(gb1 + kk, lb1);
    __syncthreads();
    bf16x8 af[4], bfr[4];
    #pragma unroll
    for (int x = 0; x < 4; ++x) {
      af[x]  = *(const bf16x8*)&As[(wm + x * 16 + l15) * 32 + l4 * 8];
      bfr[x] = *(const bf16x8*)&Bs[(wn + x * 16 + l15) * 32 + l4 * 8];
    }
    #pragma unroll
    for (int mi = 0; mi < 4; ++mi)
      #pragma unroll
      for (int ni = 0; ni < 4; ++ni)
        acc[mi][ni] = __builtin_amdgcn_mfma_f32_16x16x32_bf16(af[mi], bfr[ni], acc[mi][ni], 0, 0, 0);
    __syncthreads();
  }
  #pragma unroll
  for (int mi = 0; mi < 4; ++mi)
    #pragma unroll
    for (int ni = 0; ni < 4; ++ni)
      #pragma unroll
      for (int j = 0; j < 4; ++j) {
        long r = arow + wm + mi * 16 + l4 * 4 + j;
        long c = brow + wn + ni * 16 + l15;
        C[r * N + c] = acc[mi][ni][j];
      }
}

// ---------------- fused per-head LayerNorm + RoPE (+ v passthrough convert) ----------------
// 256 threads = 4 waves; each wave handles one t-row of head-block hh.
__global__ __launch_bounds__(256) void ln_rope_kernel(
    const float* __restrict__ qkv, const int* __restrict__ pos,
    const float* __restrict__ qw, const float* __restrict__ qb2,
    const float* __restrict__ kw, const float* __restrict__ kb2,
    u16* __restrict__ qo, u16* __restrict__ ko, u16* __restrict__ vo, int T) {
  const int hh = blockIdx.x;
  const int t = blockIdx.y * 4 + (threadIdx.x >> 6);
  const int lane = threadIdx.x & 63;
  const float* src = qkv + (size_t)t * 12288 + hh * 128;
  float x1 = src[lane], x2 = src[lane + 64];
  if (hh >= 64) {
    u16* dst = vo + ((size_t)(hh - 64) * T + t) * 128;
    dst[lane] = f2bf(x1); dst[lane + 64] = f2bf(x2);
    return;
  }
  float s = x1 + x2;
  #pragma unroll
  for (int off = 32; off; off >>= 1) s += __shfl_xor(s, off);
  float mu = s * (1.0f / 128.0f);
  float d1 = x1 - mu, d2 = x2 - mu;
  float vs = d1 * d1 + d2 * d2;
  #pragma unroll
  for (int off = 32; off; off >>= 1) vs += __shfl_xor(vs, off);
  float rstd = rsqrtf(vs * (1.0f / 128.0f) + 1e-5f);
  bool isq = hh < 32;
  int hl = isq ? hh : hh - 32;
  const float* w = (isq ? qw : kw) + hl * 128;
  const float* b = (isq ? qb2 : kb2) + hl * 128;
  float y1 = d1 * rstd * w[lane] + b[lane];
  float y2 = d2 * rstd * w[lane + 64] + b[lane + 64];
  float p = (float)pos[t];
  float invf = exp2f((float)lane * (-13.287712379549449f / 64.0f));
  float fr = p * invf;
  float sn, cs;
  __sincosf(fr, &sn, &cs);
  float o1 = y1 * cs - y2 * sn;
  float o2 = y2 * cs + y1 * sn;
  if (isq) {
    const float sc = 0.08838834764831845f;   // 1/sqrt(128) folded into q
    o1 *= sc; o2 *= sc;
    u16* dst = qo + ((size_t)hl * T + t) * 128;
    dst[lane] = f2bf(o1); dst[lane + 64] = f2bf(o2);
  } else {
    u16* dst = ko + ((size_t)hl * T + t) * 128;
    dst[lane] = f2bf(o1); dst[lane + 64] = f2bf(o2);
  }
}

// ---------------- flash attention (causal), bf16 MFMA, online softmax ----------------
// T14 async-STAGE (global->reg issued early, reg->LDS next iter), T13 defer-max,
// T5 setprio around MFMA clusters.
__global__ __launch_bounds__(256, 2) void flash_kernel(
    const u16* __restrict__ qb, const u16* __restrict__ kb,
    const u16* __restrict__ vb, u16* __restrict__ attn, int T) {
  __shared__ __align__(16) u16 Ks[64 * 128];    // K tile, row-major [kv][d], swizzled
  __shared__ __align__(16) u16 Vt[128 * 64];    // V tile transposed [d][kv], swizzled
  __shared__ __align__(16) u16 Ps[4][32 * 64];  // per-wave P buffer, swizzled
  const int tid = threadIdx.x;
  const int lane = tid & 63, wave = tid >> 6;
  const int l15 = lane & 15, l4 = lane >> 4;
  const int h = blockIdx.y;
  const int qbase = blockIdx.x * 128;
  const int qrow0 = qbase + wave * 32;
  const u16* Q  = qb + (size_t)h * T * 128;
  const u16* Kp = kb + (size_t)h * T * 128;
  const u16* Vp = vb + (size_t)h * T * 128;
  // staging map: K: row (tid>>4)+16c, 16B piece (tid&15)*8; V: row lane, d-block (wave+4c)*8
  const int rK0 = tid >> 4, d8k = (tid & 15) * 8;

  bf16x8 qf[2][4];
  #pragma unroll
  for (int mi = 0; mi < 2; ++mi)
    #pragma unroll
    for (int kc = 0; kc < 4; ++kc)
      qf[mi][kc] = *(const bf16x8*)&Q[(size_t)(qrow0 + mi * 16 + l15) * 128 + kc * 32 + l4 * 8];

  float m_st[2][4], l_st[2][4];
  f32x4 o[2][8] = {};
  #pragma unroll
  for (int mi = 0; mi < 2; ++mi)
    #pragma unroll
    for (int j = 0; j < 4; ++j) { m_st[mi][j] = -1e30f; l_st[mi][j] = 0.0f; }

  const int ntile = (qbase + 128) / 64;
  uint4 kr[4], vr[4];
  #pragma unroll
  for (int c = 0; c < 4; ++c) {
    kr[c] = *(const uint4*)&Kp[(size_t)(rK0 + 16 * c) * 128 + d8k];
    vr[c] = *(const uint4*)&Vp[(size_t)lane * 128 + (wave + 4 * c) * 8];
  }
  for (int kt = 0; kt < ntile; ++kt) {
    const int kbase = kt * 64;
    // reg -> LDS for tile kt
    #pragma unroll
    for (int c = 0; c < 4; ++c) {
      *(uint4*)&Ks[swz128i(rK0 + 16 * c, d8k)] = kr[c];
      const u16* pv = (const u16*)&vr[c];
      int dv = (wave + 4 * c) * 8;
      #pragma unroll
      for (int j = 0; j < 8; ++j) Vt[swz64i(dv + j, lane)] = pv[j];
    }
    __syncthreads();
    // issue next tile's global loads (latency hides under compute below)
    if (kt + 1 < ntile) {
      const int nb = kbase + 64;
      #pragma unroll
      for (int c = 0; c < 4; ++c) {
        kr[c] = *(const uint4*)&Kp[(size_t)(nb + rK0 + 16 * c) * 128 + d8k];
        vr[c] = *(const uint4*)&Vp[(size_t)(nb + lane) * 128 + (wave + 4 * c) * 8];
      }
    }
    if (kbase <= qrow0 + 31) {
      f32x4 s[2][4] = {};
      __builtin_amdgcn_s_setprio(1);
      #pragma unroll
      for (int kc = 0; kc < 4; ++kc)
        #pragma unroll
        for (int nj = 0; nj < 4; ++nj) {
          bf16x8 kf = *(const bf16x8*)&Ks[swz128i(nj * 16 + l15, kc * 32 + l4 * 8)];
          #pragma unroll
          for (int mi = 0; mi < 2; ++mi)
            s[mi][nj] = __builtin_amdgcn_mfma_f32_16x16x32_bf16(qf[mi][kc], kf, s[mi][nj], 0, 0, 0);
        }
      __builtin_amdgcn_s_setprio(0);
      if (kbase + 63 > qrow0) {
        #pragma unroll
        for (int mi = 0; mi < 2; ++mi)
          #pragma unroll
          for (int nj = 0; nj < 4; ++nj)
            #pragma unroll
            for (int j = 0; j < 4; ++j) {
              int r = qrow0 + mi * 16 + l4 * 4 + j;
              int cc = kbase + nj * 16 + l15;
              if (cc > r) s[mi][nj][j] = -1e30f;
            }
      }
      // row maxes + defer-max decision
      float vmax[2][4];
      float dmax = -1e30f;
      #pragma unroll
      for (int mi = 0; mi < 2; ++mi)
        #pragma unroll
        for (int j = 0; j < 4; ++j) {
          float v = fmaxf(fmaxf(s[mi][0][j], s[mi][1][j]), fmaxf(s[mi][2][j], s[mi][3][j]));
          #pragma unroll
          for (int off = 1; off < 16; off <<= 1) v = fmaxf(v, __shfl_xor(v, off));
          vmax[mi][j] = v;
          dmax = fmaxf(dmax, v - m_st[mi][j]);
        }
      if (!__all(dmax <= 8.0f)) {   // T13: rescale only when max grew enough
        #pragma unroll
        for (int mi = 0; mi < 2; ++mi)
          #pragma unroll
          for (int j = 0; j < 4; ++j) {
            float mn = fmaxf(m_st[mi][j], vmax[mi][j]);
            float scl = __expf(m_st[mi][j] - mn);
            m_st[mi][j] = mn;
            l_st[mi][j] *= scl;
            #pragma unroll
            for (int nf = 0; nf < 8; ++nf) o[mi][nf][j] *= scl;
          }
      }
      #pragma unroll
      for (int mi = 0; mi < 2; ++mi) {
        float sum[4] = {0.f, 0.f, 0.f, 0.f};
        #pragma unroll
        for (int nj = 0; nj < 4; ++nj)
          #pragma unroll
          for (int j = 0; j < 4; ++j) {
            float p = __expf(s[mi][nj][j] - m_st[mi][j]);
            s[mi][nj][j] = p;
            sum[j] += p;
          }
        #pragma unroll
        for (int j = 0; j < 4; ++j) {
          #pragma unroll
          for (int off = 1; off < 16; off <<= 1) sum[j] += __shfl_xor(sum[j], off);
          l_st[mi][j] += sum[j];
        }
        #pragma unroll
        for (int nj = 0; nj < 4; ++nj)
          #pragma unroll
          for (int j = 0; j < 4; ++j)
            Ps[wave][swz64i(mi * 16 + l4 * 4 + j, nj * 16 + l15)] = f2bf(s[mi][nj][j]);
      }
      asm volatile("s_waitcnt lgkmcnt(0)" ::: "memory");
      __builtin_amdgcn_sched_barrier(0);
      __builtin_amdgcn_s_setprio(1);
      #pragma unroll
      for (int mi = 0; mi < 2; ++mi)
        #pragma unroll
        for (int kc = 0; kc < 2; ++kc) {
          bf16x8 pf = *(const bf16x8*)&Ps[wave][swz64i(mi * 16 + l15, kc * 32 + l4 * 8)];
          #pragma unroll
          for (int nf = 0; nf < 8; ++nf) {
            bf16x8 vf = *(const bf16x8*)&Vt[swz64i(nf * 16 + l15, kc * 32 + l4 * 8)];
            o[mi][nf] = __builtin_amdgcn_mfma_f32_16x16x32_bf16(pf, vf, o[mi][nf], 0, 0, 0);
          }
        }
      __builtin_amdgcn_s_setprio(0);
    }
    __syncthreads();
  }
  #pragma unroll
  for (int mi = 0; mi < 2; ++mi) {
    float rl[4];
    #pragma unroll
    for (int j = 0; j < 4; ++j) rl[j] = 1.0f / l_st[mi][j];
    #pragma unroll
    for (int nf = 0; nf < 8; ++nf)
      #pragma unroll
      for (int j = 0; j < 4; ++j) {
        int r = qrow0 + mi * 16 + l4 * 4 + j;
        int cc = h * 128 + nf * 16 + l15;
        attn[(size_t)r * 4096 + cc] = f2bf(o[mi][nf][j] * rl[j]);
      }
  }
}

// ---------------- launch ----------------
extern "C" void kernel_launch(void* const* d_in, const int* in_sizes, int n_in,
                              void* d_out, int out_size, void* d_ws, size_t ws_size,
                              hipStream_t stream) {
  const int* positions = (const int*)d_in[0];
  const float* hidden  = (const float*)d_in[1];
  const float* w_qkv   = (const float*)d_in[2];
  const float* w_o     = (const float*)d_in[3];
  const float* qnw     = (const float*)d_in[4];
  const float* qnb     = (const float*)d_in[5];
  const float* knw     = (const float*)d_in[6];
  const float* knb     = (const float*)d_in[7];
  float* out = (float*)d_out;

  const int T = in_sizes[0];           // 2048
  const int HID = 4096, NQKV = 12288, H = 32;

  char* ws = (char*)d_ws;
  u16* hid_bf  = (u16*)ws;
  u16* wreg    = (u16*)(ws + (size_t)T * HID * 2);
  float* qkv_f = (float*)(ws + (size_t)T * HID * 2 + (size_t)NQKV * HID * 2);

  u16* q_bf  = wreg;                                 // [H][T][128]
  u16* k_bf  = q_bf + (size_t)H * T * 128;           // [H][T][128]
  u16* v_bf  = k_bf + (size_t)H * T * 128;           // [H][T][128]
  u16* at_bf = v_bf + (size_t)H * T * 128;           // [T][H*128]
  u16* wo_bf = at_bf + (size_t)T * 4096;             // [4096][4096]

  cvt_bf16_kernel<<<2048, 256, 0, stream>>>(hidden, hid_bf, (long)T * HID / 4);
  cvt_bf16_kernel<<<4096, 256, 0, stream>>>(w_qkv, wreg, (long)NQKV * HID / 4);
  gemm_bt<<<dim3(NQKV / 128, T / 128), 256, 0, stream>>>(hid_bf, wreg, qkv_f, T, NQKV, HID);
  ln_rope_kernel<<<dim3(96, T / 4), 256, 0, stream>>>(qkv_f, positions, qnw, qnb, knw, knb,
                                                      q_bf, k_bf, v_bf, T);
  cvt_bf16_kernel<<<2048, 256, 0, stream>>>(w_o, wo_bf, (long)HID * HID / 4);
  flash_kernel<<<dim3(T / 128, H), 256, 0, stream>>>(q_bf, k_bf, v_bf, at_bf, T);
  gemm_bt<<<dim3(HID / 128, T / 128), 256, 0, stream>>>(at_bf, wo_bf, out, T, HID, HID);
}

// Round 4
// 606.547 us; speedup vs baseline: 1.3166x; 1.1481x over previous
//
#include <hip/hip_runtime.h>
#include <cstdint>

typedef unsigned short u16;
typedef __attribute__((ext_vector_type(8))) __bf16 bf16x8;
typedef __attribute__((ext_vector_type(4))) float f32x4;

__device__ __forceinline__ u16 f2bf(float f) {
  unsigned int u = __builtin_bit_cast(unsigned int, f);
  unsigned int r = (u + 0x7fffu + ((u >> 16) & 1u)) >> 16;
  return (u16)r;
}

// async global->LDS, 16B per lane. LDS dest must be linear in lane (wave base + lane*16).
__device__ __forceinline__ void gload16(const u16* g, u16* l) {
  __builtin_amdgcn_global_load_lds((const __attribute__((address_space(1))) void*)g,
                                   (__attribute__((address_space(3))) void*)l, 16, 0, 0);
}

// XOR-swizzle helpers for flash kernel LDS.
__device__ __forceinline__ int swz64i(int row, int col) {   // 64 u16 cols per row
  return row * 64 + (((col & 0x38) ^ ((row & 7) << 3)) | (col & 7));
}
__device__ __forceinline__ int swz128i(int row, int col) {  // 128 u16 cols per row
  return row * 128 + (((col & 0x78) ^ ((row & 7) << 3)) | (col & 7));
}

// ---------------- fp32 -> bf16 conversion ----------------
__global__ __launch_bounds__(256) void cvt_bf16_kernel(const float* __restrict__ in,
                                                       u16* __restrict__ out, long n4) {
  long i = (long)blockIdx.x * 256 + threadIdx.x;
  long stride = (long)gridDim.x * 256;
  const float4* in4 = (const float4*)in;
  uint2* out2 = (uint2*)out;
  for (long k = i; k < n4; k += stride) {
    float4 v = in4[k];
    uint2 o;
    o.x = (unsigned int)f2bf(v.x) | ((unsigned int)f2bf(v.y) << 16);
    o.y = (unsigned int)f2bf(v.z) | ((unsigned int)f2bf(v.w) << 16);
    out2[k] = o;
  }
}

// ---------------- 256x256 8-phase bf16 GEMM (m201 template, plain HIP) --------------
// C[M][N] = A[M][K] * B[N][K]^T, fp32 C. BK=64, 8 waves (2Mx4N), dbuf 128KiB dynamic LDS.
// Per K-tile: 4 phases, each {ds_read subtile || stage gload_lds || barrier; lgkm0; 16 MFMA; barrier}.
// Counted vmcnt(6) once per K-tile. LDS swizzle: 16B chunk ^ (row&7), applied as
// pre-swizzled GLOBAL source (gload_lds dest linear) + swizzled ds_read.
// Stage schedule (race-free, derived): tile u: P1 -> (u+1).A1 ; P3 -> (u+2).B0,B1 ;
// P4 -> (u+2).A0 + vmcnt(6). Requires gridDim.y == 8, K % 64 == 0, NT >= 2.
__global__ __launch_bounds__(512, 2) void gemm256(const u16* __restrict__ A,
                                                  const u16* __restrict__ B,
                                                  float* __restrict__ C,
                                                  int Mdim, int Ndim, int Kdim) {
  extern __shared__ __align__(16) u16 lds_dyn[];   // [A: 2*16384][B: 2*16384] u16
  const int tid = threadIdx.x;
  const int lane = tid & 63, wave = tid >> 6;
  const int wr = wave >> 2, wc = wave & 3;
  const int l15 = lane & 15, l4 = lane >> 4;
  // XCD swizzle: chunk along N (bx), by-fastest within chunk (gy==8).
  int lin = blockIdx.y * gridDim.x + blockIdx.x;
  int n_ = (lin & 7) * gridDim.x + (lin >> 3);
  const int bx = n_ >> 3, by = n_ & 7;
  const long arow = (long)by * 256, brow = (long)bx * 256;
  const int NT = Kdim >> 6;

  // staging source pointers: half h, round r; row_r = (tid>>3) + r*64, pre-swizzled k-offset
  const int rowt = tid >> 3;
  const int koff = (((tid & 7) ^ ((tid >> 3) & 7))) * 8;   // u16 units
  const u16* gA[2][2];
  const u16* gB[2][2];
  #pragma unroll
  for (int h = 0; h < 2; ++h)
    #pragma unroll
    for (int r = 0; r < 2; ++r) {
      gA[h][r] = A + (size_t)(arow + h * 128 + rowt + r * 64) * Kdim + koff;
      gB[h][r] = B + (size_t)(brow + h * 128 + rowt + r * 64) * Kdim + koff;
    }
  u16* const ldsB = lds_dyn + 32768;

  // stage one half-tile (2 x gload16 per thread)
  auto STAGEA = [&](int u, int h, int b) {
    u16* d = lds_dyn + b * 16384 + h * 8192 + tid * 8;
    gload16(gA[h][0] + (size_t)u * 64, d);
    gload16(gA[h][1] + (size_t)u * 64, d + 4096);
  };
  auto STAGEB = [&](int u, int h, int b) {
    u16* d = ldsB + b * 16384 + h * 8192 + tid * 8;
    gload16(gB[h][0] + (size_t)u * 64, d);
    gload16(gB[h][1] + (size_t)u * 64, d + 4096);
  };

  bf16x8 aF[4][2], bF0[2][2], bF1[2][2];
  f32x4 acc[8][4] = {};
  const int aswz = (l15 & 7) << 3;     // u16-unit swizzle of the 16B chunk index

  auto LDA = [&](int mh, int b) {
    const u16* base = lds_dyn + b * 16384 + (wr * 128 + mh * 64 + l15) * 64;
    #pragma unroll
    for (int m = 0; m < 4; ++m)
      #pragma unroll
      for (int kc = 0; kc < 2; ++kc)
        aF[m][kc] = *(const bf16x8*)(base + m * 1024 + ((kc * 32 + l4 * 8) ^ aswz));
  };
  auto LDB = [&](int nh, int b, bf16x8 (*bf)[2]) {
    const u16* base = ldsB + b * 16384 + (wc * 64 + nh * 32 + l15) * 64;
    #pragma unroll
    for (int n = 0; n < 2; ++n)
      #pragma unroll
      for (int kc = 0; kc < 2; ++kc)
        bf[n][kc] = *(const bf16x8*)(base + n * 1024 + ((kc * 32 + l4 * 8) ^ aswz));
  };
  auto MM16 = [&](int mh, int nh, bf16x8 (*bf)[2]) {
    #pragma unroll
    for (int m = 0; m < 4; ++m)
      #pragma unroll
      for (int n = 0; n < 2; ++n)
        #pragma unroll
        for (int kc = 0; kc < 2; ++kc)
          acc[mh * 4 + m][nh * 2 + n] =
            __builtin_amdgcn_mfma_f32_16x16x32_bf16(aF[m][kc], bf[n][kc],
                                                    acc[mh * 4 + m][nh * 2 + n], 0, 0, 0);
  };

#define PH_BEGIN() do { __builtin_amdgcn_s_barrier();                         \
    asm volatile("s_waitcnt lgkmcnt(0)" ::: "memory");                        \
    __builtin_amdgcn_sched_barrier(0);                                        \
    __builtin_amdgcn_s_setprio(1); } while (0)
#define PH_END() do { __builtin_amdgcn_s_setprio(0);                          \
    __builtin_amdgcn_s_barrier(); } while (0)

  // prologue: tile0 fully + tile1 {B0,B1,A0}; vmcnt(6) leaves tile1's 6 newest in flight
  STAGEB(0, 0, 0); STAGEB(0, 1, 0); STAGEA(0, 0, 0); STAGEA(0, 1, 0);
  STAGEB(1, 0, 1); STAGEB(1, 1, 1); STAGEA(1, 0, 1);
  asm volatile("s_waitcnt vmcnt(6)" ::: "memory");
  __builtin_amdgcn_s_barrier();

  for (int u = 0; u < NT; ++u) {
    const int b = u & 1, nb = b ^ 1;
    // P1: quadrant (mh0, nh0)
    LDA(0, b); LDB(0, b, bF0);
    if (u + 1 < NT) STAGEA(u + 1, 1, nb);
    PH_BEGIN(); MM16(0, 0, bF0); PH_END();
    // P2: (mh0, nh1)
    LDB(1, b, bF1);
    PH_BEGIN(); MM16(0, 1, bF1); PH_END();
    // P3: (mh1, nh1)
    LDA(1, b);
    if (u + 2 < NT) { STAGEB(u + 2, 0, b); STAGEB(u + 2, 1, b); }
    PH_BEGIN(); MM16(1, 1, bF1); PH_END();
    // P4: (mh1, nh0)
    if (u + 2 < NT) {
      STAGEA(u + 2, 0, b);
      asm volatile("s_waitcnt vmcnt(6)" ::: "memory");
    } else if (u + 1 < NT) {
      asm volatile("s_waitcnt vmcnt(0)" ::: "memory");
    }
    PH_BEGIN(); MM16(1, 0, bF0); PH_END();
  }
#undef PH_BEGIN
#undef PH_END

  #pragma unroll
  for (int M = 0; M < 8; ++M)
    #pragma unroll
    for (int n = 0; n < 4; ++n)
      #pragma unroll
      for (int j = 0; j < 4; ++j) {
        long r = arow + wr * 128 + M * 16 + l4 * 4 + j;
        long c = brow + wc * 64 + n * 16 + l15;
        C[r * Ndim + c] = acc[M][n][j];
      }
}

// ---------------- fused per-head LayerNorm + RoPE (+ v passthrough convert) ----------------
__global__ __launch_bounds__(256) void ln_rope_kernel(
    const float* __restrict__ qkv, const int* __restrict__ pos,
    const float* __restrict__ qw, const float* __restrict__ qb2,
    const float* __restrict__ kw, const float* __restrict__ kb2,
    u16* __restrict__ qo, u16* __restrict__ ko, u16* __restrict__ vo, int T) {
  const int hh = blockIdx.x;
  const int t = blockIdx.y * 4 + (threadIdx.x >> 6);
  const int lane = threadIdx.x & 63;
  const float* src = qkv + (size_t)t * 12288 + hh * 128;
  float x1 = src[lane], x2 = src[lane + 64];
  if (hh >= 64) {
    u16* dst = vo + ((size_t)(hh - 64) * T + t) * 128;
    dst[lane] = f2bf(x1); dst[lane + 64] = f2bf(x2);
    return;
  }
  float s = x1 + x2;
  #pragma unroll
  for (int off = 32; off; off >>= 1) s += __shfl_xor(s, off);
  float mu = s * (1.0f / 128.0f);
  float d1 = x1 - mu, d2 = x2 - mu;
  float vs = d1 * d1 + d2 * d2;
  #pragma unroll
  for (int off = 32; off; off >>= 1) vs += __shfl_xor(vs, off);
  float rstd = rsqrtf(vs * (1.0f / 128.0f) + 1e-5f);
  bool isq = hh < 32;
  int hl = isq ? hh : hh - 32;
  const float* w = (isq ? qw : kw) + hl * 128;
  const float* b = (isq ? qb2 : kb2) + hl * 128;
  float y1 = d1 * rstd * w[lane] + b[lane];
  float y2 = d2 * rstd * w[lane + 64] + b[lane + 64];
  float p = (float)pos[t];
  float invf = exp2f((float)lane * (-13.287712379549449f / 64.0f));
  float fr = p * invf;
  float sn, cs;
  __sincosf(fr, &sn, &cs);
  float o1 = y1 * cs - y2 * sn;
  float o2 = y2 * cs + y1 * sn;
  if (isq) {
    const float sc = 0.08838834764831845f;   // 1/sqrt(128) folded into q
    o1 *= sc; o2 *= sc;
    u16* dst = qo + ((size_t)hl * T + t) * 128;
    dst[lane] = f2bf(o1); dst[lane + 64] = f2bf(o2);
  } else {
    u16* dst = ko + ((size_t)hl * T + t) * 128;
    dst[lane] = f2bf(o1); dst[lane + 64] = f2bf(o2);
  }
}

// ---------------- flash attention (causal), bf16 MFMA, online softmax ----------------
__global__ __launch_bounds__(256, 2) void flash_kernel(
    const u16* __restrict__ qb, const u16* __restrict__ kb,
    const u16* __restrict__ vb, u16* __restrict__ attn, int T) {
  __shared__ __align__(16) u16 Ks[64 * 128];
  __shared__ __align__(16) u16 Vt[128 * 64];
  __shared__ __align__(16) u16 Ps[4][32 * 64];
  const int tid = threadIdx.x;
  const int lane = tid & 63, wave = tid >> 6;
  const int l15 = lane & 15, l4 = lane >> 4;
  const int h = blockIdx.y;
  const int qbase = blockIdx.x * 128;
  const int qrow0 = qbase + wave * 32;
  const u16* Q  = qb + (size_t)h * T * 128;
  const u16* Kp = kb + (size_t)h * T * 128;
  const u16* Vp = vb + (size_t)h * T * 128;
  const int rK0 = tid >> 4, d8k = (tid & 15) * 8;

  bf16x8 qf[2][4];
  #pragma unroll
  for (int mi = 0; mi < 2; ++mi)
    #pragma unroll
    for (int kc = 0; kc < 4; ++kc)
      qf[mi][kc] = *(const bf16x8*)&Q[(size_t)(qrow0 + mi * 16 + l15) * 128 + kc * 32 + l4 * 8];

  float m_st[2][4], l_st[2][4];
  f32x4 o[2][8] = {};
  #pragma unroll
  for (int mi = 0; mi < 2; ++mi)
    #pragma unroll
    for (int j = 0; j < 4; ++j) { m_st[mi][j] = -1e30f; l_st[mi][j] = 0.0f; }

  const int ntile = (qbase + 128) / 64;
  uint4 kr[4], vr[4];
  #pragma unroll
  for (int c = 0; c < 4; ++c) {
    kr[c] = *(const uint4*)&Kp[(size_t)(rK0 + 16 * c) * 128 + d8k];
    vr[c] = *(const uint4*)&Vp[(size_t)lane * 128 + (wave + 4 * c) * 8];
  }
  for (int kt = 0; kt < ntile; ++kt) {
    const int kbase = kt * 64;
    #pragma unroll
    for (int c = 0; c < 4; ++c) {
      *(uint4*)&Ks[swz128i(rK0 + 16 * c, d8k)] = kr[c];
      const u16* pv = (const u16*)&vr[c];
      int dv = (wave + 4 * c) * 8;
      #pragma unroll
      for (int j = 0; j < 8; ++j) Vt[swz64i(dv + j, lane)] = pv[j];
    }
    __syncthreads();
    if (kt + 1 < ntile) {
      const int nb = kbase + 64;
      #pragma unroll
      for (int c = 0; c < 4; ++c) {
        kr[c] = *(const uint4*)&Kp[(size_t)(nb + rK0 + 16 * c) * 128 + d8k];
        vr[c] = *(const uint4*)&Vp[(size_t)(nb + lane) * 128 + (wave + 4 * c) * 8];
      }
    }
    if (kbase <= qrow0 + 31) {
      f32x4 s[2][4] = {};
      __builtin_amdgcn_s_setprio(1);
      #pragma unroll
      for (int kc = 0; kc < 4; ++kc)
        #pragma unroll
        for (int nj = 0; nj < 4; ++nj) {
          bf16x8 kf = *(const bf16x8*)&Ks[swz128i(nj * 16 + l15, kc * 32 + l4 * 8)];
          #pragma unroll
          for (int mi = 0; mi < 2; ++mi)
            s[mi][nj] = __builtin_amdgcn_mfma_f32_16x16x32_bf16(qf[mi][kc], kf, s[mi][nj], 0, 0, 0);
        }
      __builtin_amdgcn_s_setprio(0);
      if (kbase + 63 > qrow0) {
        #pragma unroll
        for (int mi = 0; mi < 2; ++mi)
          #pragma unroll
          for (int nj = 0; nj < 4; ++nj)
            #pragma unroll
            for (int j = 0; j < 4; ++j) {
              int r = qrow0 + mi * 16 + l4 * 4 + j;
              int cc = kbase + nj * 16 + l15;
              if (cc > r) s[mi][nj][j] = -1e30f;
            }
      }
      float vmax[2][4];
      float dmax = -1e30f;
      #pragma unroll
      for (int mi = 0; mi < 2; ++mi)
        #pragma unroll
        for (int j = 0; j < 4; ++j) {
          float v = fmaxf(fmaxf(s[mi][0][j], s[mi][1][j]), fmaxf(s[mi][2][j], s[mi][3][j]));
          #pragma unroll
          for (int off = 1; off < 16; off <<= 1) v = fmaxf(v, __shfl_xor(v, off));
          vmax[mi][j] = v;
          dmax = fmaxf(dmax, v - m_st[mi][j]);
        }
      if (!__all(dmax <= 8.0f)) {
        #pragma unroll
        for (int mi = 0; mi < 2; ++mi)
          #pragma unroll
          for (int j = 0; j < 4; ++j) {
            float mn = fmaxf(m_st[mi][j], vmax[mi][j]);
            float scl = __expf(m_st[mi][j] - mn);
            m_st[mi][j] = mn;
            l_st[mi][j] *= scl;
            #pragma unroll
            for (int nf = 0; nf < 8; ++nf) o[mi][nf][j] *= scl;
          }
      }
      #pragma unroll
      for (int mi = 0; mi < 2; ++mi) {
        float sum[4] = {0.f, 0.f, 0.f, 0.f};
        #pragma unroll
        for (int nj = 0; nj < 4; ++nj)
          #pragma unroll
          for (int j = 0; j < 4; ++j) {
            float p = __expf(s[mi][nj][j] - m_st[mi][j]);
            s[mi][nj][j] = p;
            sum[j] += p;
          }
        #pragma unroll
        for (int j = 0; j < 4; ++j) {
          #pragma unroll
          for (int off = 1; off < 16; off <<= 1) sum[j] += __shfl_xor(sum[j], off);
          l_st[mi][j] += sum[j];
        }
        #pragma unroll
        for (int nj = 0; nj < 4; ++nj)
          #pragma unroll
          for (int j = 0; j < 4; ++j)
            Ps[wave][swz64i(mi * 16 + l4 * 4 + j, nj * 16 + l15)] = f2bf(s[mi][nj][j]);
      }
      asm volatile("s_waitcnt lgkmcnt(0)" ::: "memory");
      __builtin_amdgcn_sched_barrier(0);
      __builtin_amdgcn_s_setprio(1);
      #pragma unroll
      for (int mi = 0; mi < 2; ++mi)
        #pragma unroll
        for (int kc = 0; kc < 2; ++kc) {
          bf16x8 pf = *(const bf16x8*)&Ps[wave][swz64i(mi * 16 + l15, kc * 32 + l4 * 8)];
          #pragma unroll
          for (int nf = 0; nf < 8; ++nf) {
            bf16x8 vf = *(const bf16x8*)&Vt[swz64i(nf * 16 + l15, kc * 32 + l4 * 8)];
            o[mi][nf] = __builtin_amdgcn_mfma_f32_16x16x32_bf16(pf, vf, o[mi][nf], 0, 0, 0);
          }
        }
      __builtin_amdgcn_s_setprio(0);
    }
    __syncthreads();
  }
  #pragma unroll
  for (int mi = 0; mi < 2; ++mi) {
    float rl[4];
    #pragma unroll
    for (int j = 0; j < 4; ++j) rl[j] = 1.0f / l_st[mi][j];
    #pragma unroll
    for (int nf = 0; nf < 8; ++nf)
      #pragma unroll
      for (int j = 0; j < 4; ++j) {
        int r = qrow0 + mi * 16 + l4 * 4 + j;
        int cc = h * 128 + nf * 16 + l15;
        attn[(size_t)r * 4096 + cc] = f2bf(o[mi][nf][j] * rl[j]);
      }
  }
}

// ---------------- launch ----------------
extern "C" void kernel_launch(void* const* d_in, const int* in_sizes, int n_in,
                              void* d_out, int out_size, void* d_ws, size_t ws_size,
                              hipStream_t stream) {
  const int* positions = (const int*)d_in[0];
  const float* hidden  = (const float*)d_in[1];
  const float* w_qkv   = (const float*)d_in[2];
  const float* w_o     = (const float*)d_in[3];
  const float* qnw     = (const float*)d_in[4];
  const float* qnb     = (const float*)d_in[5];
  const float* knw     = (const float*)d_in[6];
  const float* knb     = (const float*)d_in[7];
  float* out = (float*)d_out;

  const int T = in_sizes[0];           // 2048
  const int HID = 4096, NQKV = 12288, H = 32;

  char* ws = (char*)d_ws;
  u16* hid_bf  = (u16*)ws;
  u16* wreg    = (u16*)(ws + (size_t)T * HID * 2);
  float* qkv_f = (float*)(ws + (size_t)T * HID * 2 + (size_t)NQKV * HID * 2);

  u16* q_bf  = wreg;                                 // [H][T][128]
  u16* k_bf  = q_bf + (size_t)H * T * 128;           // [H][T][128]
  u16* v_bf  = k_bf + (size_t)H * T * 128;           // [H][T][128]
  u16* at_bf = v_bf + (size_t)H * T * 128;           // [T][H*128]
  u16* wo_bf = at_bf + (size_t)T * 4096;             // [4096][4096]

  hipFuncSetAttribute(reinterpret_cast<const void*>(&gemm256),
                      hipFuncAttributeMaxDynamicSharedMemorySize, 131072);

  cvt_bf16_kernel<<<2048, 256, 0, stream>>>(hidden, hid_bf, (long)T * HID / 4);
  cvt_bf16_kernel<<<4096, 256, 0, stream>>>(w_qkv, wreg, (long)NQKV * HID / 4);
  gemm256<<<dim3(NQKV / 256, T / 256), 512, 131072, stream>>>(hid_bf, wreg, qkv_f, T, NQKV, HID);
  ln_rope_kernel<<<dim3(96, T / 4), 256, 0, stream>>>(qkv_f, positions, qnw, qnb, knw, knb,
                                                      q_bf, k_bf, v_bf, T);
  cvt_bf16_kernel<<<2048, 256, 0, stream>>>(w_o, wo_bf, (long)HID * HID / 4);
  flash_kernel<<<dim3(T / 128, H), 256, 0, stream>>>(q_bf, k_bf, v_bf, at_bf, T);
  gemm256<<<dim3(HID / 256, T / 256), 512, 131072, stream>>>(at_bf, wo_bf, out, T, HID, HID);
}

// Round 5
// 560.227 us; speedup vs baseline: 1.4255x; 1.0827x over previous
//
#include <hip/hip_runtime.h>
#include <cstdint>

typedef unsigned short u16;
typedef __attribute__((ext_vector_type(8))) __bf16 bf16x8;
typedef __attribute__((ext_vector_type(4))) float f32x4;

__device__ __forceinline__ u16 f2bf(float f) {
  unsigned int u = __builtin_bit_cast(unsigned int, f);
  unsigned int r = (u + 0x7fffu + ((u >> 16) & 1u)) >> 16;
  return (u16)r;
}

// async global->LDS, 16B per lane. LDS dest must be linear in lane (wave base + lane*16).
__device__ __forceinline__ void gload16(const u16* g, u16* l) {
  __builtin_amdgcn_global_load_lds((const __attribute__((address_space(1))) void*)g,
                                   (__attribute__((address_space(3))) void*)l, 16, 0, 0);
}

// XOR-swizzle helpers for flash kernel LDS.
__device__ __forceinline__ int swz64i(int row, int col) {   // 64 u16 cols per row
  return row * 64 + (((col & 0x38) ^ ((row & 7) << 3)) | (col & 7));
}
__device__ __forceinline__ int swz128i(int row, int col) {  // 128 u16 cols per row
  return row * 128 + (((col & 0x78) ^ ((row & 7) << 3)) | (col & 7));
}

// ---------------- fp32 -> bf16 conversion ----------------
__global__ __launch_bounds__(256) void cvt_bf16_kernel(const float* __restrict__ in,
                                                       u16* __restrict__ out, long n4) {
  long i = (long)blockIdx.x * 256 + threadIdx.x;
  long stride = (long)gridDim.x * 256;
  const float4* in4 = (const float4*)in;
  uint2* out2 = (uint2*)out;
  for (long k = i; k < n4; k += stride) {
    float4 v = in4[k];
    uint2 o;
    o.x = (unsigned int)f2bf(v.x) | ((unsigned int)f2bf(v.y) << 16);
    o.y = (unsigned int)f2bf(v.z) | ((unsigned int)f2bf(v.w) << 16);
    out2[k] = o;
  }
}

// ---------------- 256x128 2-phase bf16 GEMM, balanced grid, deep staging --------------
// C[M][N] = A[M][K] * B[N][K]^T, fp32 C. BK=64, 512 thr (8 waves, 2M x 4N; wave=128x32).
// LDS 128KiB dynamic: A triple-buffered (3x32KB, staged 2 tiles ahead at P1),
// B double-buffered (2x16KB, staged 2 ahead at P2). vmcnt(6) once per K-tile.
// Swizzle: 16B chunk ^ (row&7) via pre-swizzled global source + swizzled ds_read.
// Requires gridDim.x % 8 == 0, gridDim.y == M/256, K % 64 == 0, K/64 >= 2.
__global__ __launch_bounds__(512, 2) void gemm256(const u16* __restrict__ A,
                                                  const u16* __restrict__ B,
                                                  float* __restrict__ C,
                                                  int Ndim, int Kdim) {
  extern __shared__ __align__(16) u16 lds[];   // A: 3*16384 u16, B at 49152: 2*8192 u16
  const int tid = threadIdx.x;
  const int lane = tid & 63, wave = tid >> 6;
  const int wr = wave >> 2, wc = wave & 3;
  const int l15 = lane & 15, l4 = lane >> 4;
  // XCD swizzle: each XCD owns a contiguous bx-range x all by (bijective, gx%8==0).
  const int gx = gridDim.x;
  int lin = blockIdx.y * gx + blockIdx.x;
  const int xcd = lin & 7, ii = lin >> 3;
  const int bx = xcd * (gx >> 3) + (ii >> 3), by = ii & 7;
  const long arow = (long)by * 256, brow = (long)bx * 128;
  const int NT = Kdim >> 6;

  // staging sources: row rowt + r*64, pre-swizzled 16B chunk within the 64-col K-slab
  const int rowt = tid >> 3;
  const int koff = ((tid & 7) ^ (rowt & 7)) * 8;
  const u16* gA[4];
  const u16* gB[2];
  #pragma unroll
  for (int r = 0; r < 4; ++r) gA[r] = A + (size_t)(arow + rowt + r * 64) * Kdim + koff;
  #pragma unroll
  for (int r = 0; r < 2; ++r) gB[r] = B + (size_t)(brow + rowt + r * 64) * Kdim + koff;

  auto STA = [&](int u) {   // 4 x gload16 : 256x64 A-tile into A-buf u%3
    u16* d = lds + (u % 3) * 16384 + tid * 8;
    #pragma unroll
    for (int r = 0; r < 4; ++r) gload16(gA[r] + (size_t)u * 64, d + r * 4096);
  };
  auto STB = [&](int u) {   // 2 x gload16 : 128x64 B-tile into B-buf u&1
    u16* d = lds + 49152 + (u & 1) * 8192 + tid * 8;
    #pragma unroll
    for (int r = 0; r < 2; ++r) gload16(gB[r] + (size_t)u * 64, d + r * 4096);
  };

  bf16x8 af[4][2], bfr[2][2];
  f32x4 acc[8][2] = {};
  // swizzled chunk offset (u16 units) for ds_read: chunk = (kc*4 + l4) ^ (row&7), row&7 == l15&7
  int cks[2];
  #pragma unroll
  for (int kc = 0; kc < 2; ++kc) cks[kc] = (((kc * 4 + l4) ^ (l15 & 7)) * 8);

  auto LDA = [&](int u, int mh) {   // 8 x ds_read_b128: m-frags mh*4..mh*4+3, both kc
    const u16* base = lds + (u % 3) * 16384 + (wr * 128 + mh * 64 + l15) * 64;
    #pragma unroll
    for (int m = 0; m < 4; ++m)
      #pragma unroll
      for (int kc = 0; kc < 2; ++kc)
        af[m][kc] = *(const bf16x8*)(base + m * 1024 + cks[kc]);
  };
  auto LDB = [&](int u) {           // 4 x ds_read_b128: n-frags 0..1, both kc
    const u16* base = lds + 49152 + (u & 1) * 8192 + (wc * 32 + l15) * 64;
    #pragma unroll
    for (int n = 0; n < 2; ++n)
      #pragma unroll
      for (int kc = 0; kc < 2; ++kc)
        bfr[n][kc] = *(const bf16x8*)(base + n * 1024 + cks[kc]);
  };
  auto MM = [&](int mh) {           // 16 MFMA
    #pragma unroll
    for (int m = 0; m < 4; ++m)
      #pragma unroll
      for (int n = 0; n < 2; ++n)
        #pragma unroll
        for (int kc = 0; kc < 2; ++kc)
          acc[mh * 4 + m][n] =
            __builtin_amdgcn_mfma_f32_16x16x32_bf16(af[m][kc], bfr[n][kc],
                                                    acc[mh * 4 + m][n], 0, 0, 0);
  };

#define PH_BEGIN() do { __builtin_amdgcn_s_barrier();                         \
    asm volatile("s_waitcnt lgkmcnt(0)" ::: "memory");                        \
    __builtin_amdgcn_sched_barrier(0);                                        \
    __builtin_amdgcn_s_setprio(1); } while (0)

  // prologue: tiles 0 and 1; vmcnt(6) drains tile0 (A0+B0), leaves A1+B1 in flight
  STA(0); STB(0); STA(1); STB(1);
  asm volatile("s_waitcnt vmcnt(6)" ::: "memory");
  __builtin_amdgcn_s_barrier();

  for (int u = 0; u < NT; ++u) {
    // P1: m-half 0
    LDA(u, 0); LDB(u);
    if (u + 2 < NT) STA(u + 2);
    PH_BEGIN(); MM(0);
    __builtin_amdgcn_s_setprio(0);
    __builtin_amdgcn_s_barrier();
    // P2: m-half 1
    LDA(u, 1);
    if (u + 2 < NT) STB(u + 2);
    PH_BEGIN(); MM(1);
    __builtin_amdgcn_s_setprio(0);
    if (u + 2 < NT) { asm volatile("s_waitcnt vmcnt(6)" ::: "memory"); }
    else if (u + 1 < NT) { asm volatile("s_waitcnt vmcnt(0)" ::: "memory"); }
    __builtin_amdgcn_s_barrier();
  }
#undef PH_BEGIN

  #pragma unroll
  for (int M = 0; M < 8; ++M)
    #pragma unroll
    for (int n = 0; n < 2; ++n)
      #pragma unroll
      for (int j = 0; j < 4; ++j) {
        long r = arow + wr * 128 + M * 16 + l4 * 4 + j;
        long c = brow + wc * 32 + n * 16 + l15;
        C[r * Ndim + c] = acc[M][n][j];
      }
}

// ---------------- fused per-head LayerNorm + RoPE (+ v passthrough convert) ----------------
__global__ __launch_bounds__(256) void ln_rope_kernel(
    const float* __restrict__ qkv, const int* __restrict__ pos,
    const float* __restrict__ qw, const float* __restrict__ qb2,
    const float* __restrict__ kw, const float* __restrict__ kb2,
    u16* __restrict__ qo, u16* __restrict__ ko, u16* __restrict__ vo, int T) {
  const int hh = blockIdx.x;
  const int t = blockIdx.y * 4 + (threadIdx.x >> 6);
  const int lane = threadIdx.x & 63;
  const float* src = qkv + (size_t)t * 12288 + hh * 128;
  float x1 = src[lane], x2 = src[lane + 64];
  if (hh >= 64) {
    u16* dst = vo + ((size_t)(hh - 64) * T + t) * 128;
    dst[lane] = f2bf(x1); dst[lane + 64] = f2bf(x2);
    return;
  }
  float s = x1 + x2;
  #pragma unroll
  for (int off = 32; off; off >>= 1) s += __shfl_xor(s, off);
  float mu = s * (1.0f / 128.0f);
  float d1 = x1 - mu, d2 = x2 - mu;
  float vs = d1 * d1 + d2 * d2;
  #pragma unroll
  for (int off = 32; off; off >>= 1) vs += __shfl_xor(vs, off);
  float rstd = rsqrtf(vs * (1.0f / 128.0f) + 1e-5f);
  bool isq = hh < 32;
  int hl = isq ? hh : hh - 32;
  const float* w = (isq ? qw : kw) + hl * 128;
  const float* b = (isq ? qb2 : kb2) + hl * 128;
  float y1 = d1 * rstd * w[lane] + b[lane];
  float y2 = d2 * rstd * w[lane + 64] + b[lane + 64];
  float p = (float)pos[t];
  float invf = exp2f((float)lane * (-13.287712379549449f / 64.0f));
  float fr = p * invf;
  float sn, cs;
  __sincosf(fr, &sn, &cs);
  float o1 = y1 * cs - y2 * sn;
  float o2 = y2 * cs + y1 * sn;
  if (isq) {
    const float sc = 0.08838834764831845f;   // 1/sqrt(128) folded into q
    o1 *= sc; o2 *= sc;
    u16* dst = qo + ((size_t)hl * T + t) * 128;
    dst[lane] = f2bf(o1); dst[lane + 64] = f2bf(o2);
  } else {
    u16* dst = ko + ((size_t)hl * T + t) * 128;
    dst[lane] = f2bf(o1); dst[lane + 64] = f2bf(o2);
  }
}

// ---------------- flash attention (causal), bf16 MFMA, online softmax ----------------
__global__ __launch_bounds__(256, 2) void flash_kernel(
    const u16* __restrict__ qb, const u16* __restrict__ kb,
    const u16* __restrict__ vb, u16* __restrict__ attn, int T) {
  __shared__ __align__(16) u16 Ks[64 * 128];
  __shared__ __align__(16) u16 Vt[128 * 64];
  __shared__ __align__(16) u16 Ps[4][32 * 64];
  const int tid = threadIdx.x;
  const int lane = tid & 63, wave = tid >> 6;
  const int l15 = lane & 15, l4 = lane >> 4;
  const int h = blockIdx.y;
  const int qbase = blockIdx.x * 128;
  const int qrow0 = qbase + wave * 32;
  const u16* Q  = qb + (size_t)h * T * 128;
  const u16* Kp = kb + (size_t)h * T * 128;
  const u16* Vp = vb + (size_t)h * T * 128;
  const int rK0 = tid >> 4, d8k = (tid & 15) * 8;

  bf16x8 qf[2][4];
  #pragma unroll
  for (int mi = 0; mi < 2; ++mi)
    #pragma unroll
    for (int kc = 0; kc < 4; ++kc)
      qf[mi][kc] = *(const bf16x8*)&Q[(size_t)(qrow0 + mi * 16 + l15) * 128 + kc * 32 + l4 * 8];

  float m_st[2][4], l_st[2][4];
  f32x4 o[2][8] = {};
  #pragma unroll
  for (int mi = 0; mi < 2; ++mi)
    #pragma unroll
    for (int j = 0; j < 4; ++j) { m_st[mi][j] = -1e30f; l_st[mi][j] = 0.0f; }

  const int ntile = (qbase + 128) / 64;
  uint4 kr[4], vr[4];
  #pragma unroll
  for (int c = 0; c < 4; ++c) {
    kr[c] = *(const uint4*)&Kp[(size_t)(rK0 + 16 * c) * 128 + d8k];
    vr[c] = *(const uint4*)&Vp[(size_t)lane * 128 + (wave + 4 * c) * 8];
  }
  for (int kt = 0; kt < ntile; ++kt) {
    const int kbase = kt * 64;
    #pragma unroll
    for (int c = 0; c < 4; ++c) {
      *(uint4*)&Ks[swz128i(rK0 + 16 * c, d8k)] = kr[c];
      const u16* pv = (const u16*)&vr[c];
      int dv = (wave + 4 * c) * 8;
      #pragma unroll
      for (int j = 0; j < 8; ++j) Vt[swz64i(dv + j, lane)] = pv[j];
    }
    __syncthreads();
    if (kt + 1 < ntile) {
      const int nb = kbase + 64;
      #pragma unroll
      for (int c = 0; c < 4; ++c) {
        kr[c] = *(const uint4*)&Kp[(size_t)(nb + rK0 + 16 * c) * 128 + d8k];
        vr[c] = *(const uint4*)&Vp[(size_t)(nb + lane) * 128 + (wave + 4 * c) * 8];
      }
    }
    if (kbase <= qrow0 + 31) {
      f32x4 s[2][4] = {};
      __builtin_amdgcn_s_setprio(1);
      #pragma unroll
      for (int kc = 0; kc < 4; ++kc)
        #pragma unroll
        for (int nj = 0; nj < 4; ++nj) {
          bf16x8 kf = *(const bf16x8*)&Ks[swz128i(nj * 16 + l15, kc * 32 + l4 * 8)];
          #pragma unroll
          for (int mi = 0; mi < 2; ++mi)
            s[mi][nj] = __builtin_amdgcn_mfma_f32_16x16x32_bf16(qf[mi][kc], kf, s[mi][nj], 0, 0, 0);
        }
      __builtin_amdgcn_s_setprio(0);
      if (kbase + 63 > qrow0) {
        #pragma unroll
        for (int mi = 0; mi < 2; ++mi)
          #pragma unroll
          for (int nj = 0; nj < 4; ++nj)
            #pragma unroll
            for (int j = 0; j < 4; ++j) {
              int r = qrow0 + mi * 16 + l4 * 4 + j;
              int cc = kbase + nj * 16 + l15;
              if (cc > r) s[mi][nj][j] = -1e30f;
            }
      }
      float vmax[2][4];
      float dmax = -1e30f;
      #pragma unroll
      for (int mi = 0; mi < 2; ++mi)
        #pragma unroll
        for (int j = 0; j < 4; ++j) {
          float v = fmaxf(fmaxf(s[mi][0][j], s[mi][1][j]), fmaxf(s[mi][2][j], s[mi][3][j]));
          #pragma unroll
          for (int off = 1; off < 16; off <<= 1) v = fmaxf(v, __shfl_xor(v, off));
          vmax[mi][j] = v;
          dmax = fmaxf(dmax, v - m_st[mi][j]);
        }
      if (!__all(dmax <= 8.0f)) {
        #pragma unroll
        for (int mi = 0; mi < 2; ++mi)
          #pragma unroll
          for (int j = 0; j < 4; ++j) {
            float mn = fmaxf(m_st[mi][j], vmax[mi][j]);
            float scl = __expf(m_st[mi][j] - mn);
            m_st[mi][j] = mn;
            l_st[mi][j] *= scl;
            #pragma unroll
            for (int nf = 0; nf < 8; ++nf) o[mi][nf][j] *= scl;
          }
      }
      #pragma unroll
      for (int mi = 0; mi < 2; ++mi) {
        float sum[4] = {0.f, 0.f, 0.f, 0.f};
        #pragma unroll
        for (int nj = 0; nj < 4; ++nj)
          #pragma unroll
          for (int j = 0; j < 4; ++j) {
            float p = __expf(s[mi][nj][j] - m_st[mi][j]);
            s[mi][nj][j] = p;
            sum[j] += p;
          }
        #pragma unroll
        for (int j = 0; j < 4; ++j) {
          #pragma unroll
          for (int off = 1; off < 16; off <<= 1) sum[j] += __shfl_xor(sum[j], off);
          l_st[mi][j] += sum[j];
        }
        #pragma unroll
        for (int nj = 0; nj < 4; ++nj)
          #pragma unroll
          for (int j = 0; j < 4; ++j)
            Ps[wave][swz64i(mi * 16 + l4 * 4 + j, nj * 16 + l15)] = f2bf(s[mi][nj][j]);
      }
      asm volatile("s_waitcnt lgkmcnt(0)" ::: "memory");
      __builtin_amdgcn_sched_barrier(0);
      __builtin_amdgcn_s_setprio(1);
      #pragma unroll
      for (int mi = 0; mi < 2; ++mi)
        #pragma unroll
        for (int kc = 0; kc < 2; ++kc) {
          bf16x8 pf = *(const bf16x8*)&Ps[wave][swz64i(mi * 16 + l15, kc * 32 + l4 * 8)];
          #pragma unroll
          for (int nf = 0; nf < 8; ++nf) {
            bf16x8 vf = *(const bf16x8*)&Vt[swz64i(nf * 16 + l15, kc * 32 + l4 * 8)];
            o[mi][nf] = __builtin_amdgcn_mfma_f32_16x16x32_bf16(pf, vf, o[mi][nf], 0, 0, 0);
          }
        }
      __builtin_amdgcn_s_setprio(0);
    }
    __syncthreads();
  }
  #pragma unroll
  for (int mi = 0; mi < 2; ++mi) {
    float rl[4];
    #pragma unroll
    for (int j = 0; j < 4; ++j) rl[j] = 1.0f / l_st[mi][j];
    #pragma unroll
    for (int nf = 0; nf < 8; ++nf)
      #pragma unroll
      for (int j = 0; j < 4; ++j) {
        int r = qrow0 + mi * 16 + l4 * 4 + j;
        int cc = h * 128 + nf * 16 + l15;
        attn[(size_t)r * 4096 + cc] = f2bf(o[mi][nf][j] * rl[j]);
      }
  }
}

// ---------------- launch ----------------
extern "C" void kernel_launch(void* const* d_in, const int* in_sizes, int n_in,
                              void* d_out, int out_size, void* d_ws, size_t ws_size,
                              hipStream_t stream) {
  const int* positions = (const int*)d_in[0];
  const float* hidden  = (const float*)d_in[1];
  const float* w_qkv   = (const float*)d_in[2];
  const float* w_o     = (const float*)d_in[3];
  const float* qnw     = (const float*)d_in[4];
  const float* qnb     = (const float*)d_in[5];
  const float* knw     = (const float*)d_in[6];
  const float* knb     = (const float*)d_in[7];
  float* out = (float*)d_out;

  const int T = in_sizes[0];           // 2048
  const int HID = 4096, NQKV = 12288, H = 32;

  char* ws = (char*)d_ws;
  u16* hid_bf  = (u16*)ws;
  u16* wreg    = (u16*)(ws + (size_t)T * HID * 2);
  float* qkv_f = (float*)(ws + (size_t)T * HID * 2 + (size_t)NQKV * HID * 2);

  u16* q_bf  = wreg;                                 // [H][T][128]
  u16* k_bf  = q_bf + (size_t)H * T * 128;           // [H][T][128]
  u16* v_bf  = k_bf + (size_t)H * T * 128;           // [H][T][128]
  u16* at_bf = v_bf + (size_t)H * T * 128;           // [T][H*128]
  u16* wo_bf = at_bf + (size_t)T * 4096;             // [4096][4096]

  hipFuncSetAttribute(reinterpret_cast<const void*>(&gemm256),
                      hipFuncAttributeMaxDynamicSharedMemorySize, 131072);

  cvt_bf16_kernel<<<2048, 256, 0, stream>>>(hidden, hid_bf, (long)T * HID / 4);
  cvt_bf16_kernel<<<4096, 256, 0, stream>>>(w_qkv, wreg, (long)NQKV * HID / 4);
  gemm256<<<dim3(NQKV / 128, T / 256), 512, 131072, stream>>>(hid_bf, wreg, qkv_f, NQKV, HID);
  ln_rope_kernel<<<dim3(96, T / 4), 256, 0, stream>>>(qkv_f, positions, qnw, qnb, knw, knb,
                                                      q_bf, k_bf, v_bf, T);
  cvt_bf16_kernel<<<2048, 256, 0, stream>>>(w_o, wo_bf, (long)HID * HID / 4);
  flash_kernel<<<dim3(T / 128, H), 256, 0, stream>>>(q_bf, k_bf, v_bf, at_bf, T);
  gemm256<<<dim3(HID / 128, T / 256), 512, 131072, stream>>>(at_bf, wo_bf, out, HID, HID);
}

// Round 6
// 559.509 us; speedup vs baseline: 1.4273x; 1.0013x over previous
//
#include <hip/hip_runtime.h>
#include <cstdint>

typedef unsigned short u16;
typedef __attribute__((ext_vector_type(8))) __bf16 bf16x8;
typedef __attribute__((ext_vector_type(4))) float f32x4;

__device__ __forceinline__ u16 f2bf(float f) {
  unsigned int u = __builtin_bit_cast(unsigned int, f);
  unsigned int r = (u + 0x7fffu + ((u >> 16) & 1u)) >> 16;
  return (u16)r;
}

// async global->LDS, 16B per lane. LDS dest must be linear in lane (wave base + lane*16).
__device__ __forceinline__ void gload16(const u16* g, u16* l) {
  __builtin_amdgcn_global_load_lds((const __attribute__((address_space(1))) void*)g,
                                   (__attribute__((address_space(3))) void*)l, 16, 0, 0);
}

// XOR-swizzle helpers for flash kernel LDS.
__device__ __forceinline__ int swz64i(int row, int col) {   // 64 u16 cols per row
  return row * 64 + (((col & 0x38) ^ ((row & 7) << 3)) | (col & 7));
}
__device__ __forceinline__ int swz128i(int row, int col) {  // 128 u16 cols per row
  return row * 128 + (((col & 0x78) ^ ((row & 7) << 3)) | (col & 7));
}

// ---------------- fp32 -> bf16 conversion ----------------
__global__ __launch_bounds__(256) void cvt_bf16_kernel(const float* __restrict__ in,
                                                       u16* __restrict__ out, long n4) {
  long i = (long)blockIdx.x * 256 + threadIdx.x;
  long stride = (long)gridDim.x * 256;
  const float4* in4 = (const float4*)in;
  uint2* out2 = (uint2*)out;
  for (long k = i; k < n4; k += stride) {
    float4 v = in4[k];
    uint2 o;
    o.x = (unsigned int)f2bf(v.x) | ((unsigned int)f2bf(v.y) << 16);
    o.y = (unsigned int)f2bf(v.z) | ((unsigned int)f2bf(v.w) << 16);
    out2[k] = o;
  }
}

// ---------------- 256x128 2-phase bf16 GEMM, balanced grid, deep staging --------------
// C[M][N] = A[M][K] * B[N][K]^T, fp32 C. BK=64, 512 thr (8 waves, 2M x 4N; wave=128x32).
// LDS 128KiB dynamic: A triple-buffered (3x32KB, staged 2 tiles ahead at P1),
// B double-buffered (2x16KB, staged 2 ahead at P2). vmcnt(6) once per K-tile.
// Swizzle: 16B chunk ^ (row&7) via pre-swizzled global source + swizzled ds_read.
// MFMA issue order: kc OUTERMOST so no back-to-back dependent MFMAs on one acc.
// Requires gridDim.x % 8 == 0, gridDim.y == M/256, K % 64 == 0, K/64 >= 2.
__global__ __launch_bounds__(512, 2) void gemm256(const u16* __restrict__ A,
                                                  const u16* __restrict__ B,
                                                  float* __restrict__ C,
                                                  int Ndim, int Kdim) {
  extern __shared__ __align__(16) u16 lds[];   // A: 3*16384 u16, B at 49152: 2*8192 u16
  const int tid = threadIdx.x;
  const int lane = tid & 63, wave = tid >> 6;
  const int wr = wave >> 2, wc = wave & 3;
  const int l15 = lane & 15, l4 = lane >> 4;
  // XCD swizzle: each XCD owns a contiguous bx-range x all by (bijective, gx%8==0).
  const int gx = gridDim.x;
  int lin = blockIdx.y * gx + blockIdx.x;
  const int xcd = lin & 7, ii = lin >> 3;
  const int bx = xcd * (gx >> 3) + (ii >> 3), by = ii & 7;
  const long arow = (long)by * 256, brow = (long)bx * 128;
  const int NT = Kdim >> 6;

  // staging sources: row rowt + r*64, pre-swizzled 16B chunk within the 64-col K-slab
  const int rowt = tid >> 3;
  const int koff = ((tid & 7) ^ (rowt & 7)) * 8;
  const u16* gA[4];
  const u16* gB[2];
  #pragma unroll
  for (int r = 0; r < 4; ++r) gA[r] = A + (size_t)(arow + rowt + r * 64) * Kdim + koff;
  #pragma unroll
  for (int r = 0; r < 2; ++r) gB[r] = B + (size_t)(brow + rowt + r * 64) * Kdim + koff;

  auto STA = [&](int u) {   // 4 x gload16 : 256x64 A-tile into A-buf u%3
    u16* d = lds + (u % 3) * 16384 + tid * 8;
    #pragma unroll
    for (int r = 0; r < 4; ++r) gload16(gA[r] + (size_t)u * 64, d + r * 4096);
  };
  auto STB = [&](int u) {   // 2 x gload16 : 128x64 B-tile into B-buf u&1
    u16* d = lds + 49152 + (u & 1) * 8192 + tid * 8;
    #pragma unroll
    for (int r = 0; r < 2; ++r) gload16(gB[r] + (size_t)u * 64, d + r * 4096);
  };

  bf16x8 af[4][2], bfr[2][2];
  f32x4 acc[8][2] = {};
  // swizzled chunk offset (u16 units) for ds_read: chunk = (kc*4 + l4) ^ (row&7), row&7 == l15&7
  int cks[2];
  #pragma unroll
  for (int kc = 0; kc < 2; ++kc) cks[kc] = (((kc * 4 + l4) ^ (l15 & 7)) * 8);

  auto LDA = [&](int u, int mh) {   // 8 x ds_read_b128: m-frags mh*4..mh*4+3, both kc
    const u16* base = lds + (u % 3) * 16384 + (wr * 128 + mh * 64 + l15) * 64;
    #pragma unroll
    for (int m = 0; m < 4; ++m)
      #pragma unroll
      for (int kc = 0; kc < 2; ++kc)
        af[m][kc] = *(const bf16x8*)(base + m * 1024 + cks[kc]);
  };
  auto LDB = [&](int u) {           // 4 x ds_read_b128: n-frags 0..1, both kc
    const u16* base = lds + 49152 + (u & 1) * 8192 + (wc * 32 + l15) * 64;
    #pragma unroll
    for (int n = 0; n < 2; ++n)
      #pragma unroll
      for (int kc = 0; kc < 2; ++kc)
        bfr[n][kc] = *(const bf16x8*)(base + n * 1024 + cks[kc]);
  };
  auto MM = [&](int mh) {           // 16 MFMA, kc outermost: acc reuse 8 insts apart
    #pragma unroll
    for (int kc = 0; kc < 2; ++kc)
      #pragma unroll
      for (int m = 0; m < 4; ++m)
        #pragma unroll
        for (int n = 0; n < 2; ++n)
          acc[mh * 4 + m][n] =
            __builtin_amdgcn_mfma_f32_16x16x32_bf16(af[m][kc], bfr[n][kc],
                                                    acc[mh * 4 + m][n], 0, 0, 0);
  };

#define PH_BEGIN() do { __builtin_amdgcn_s_barrier();                         \
    asm volatile("s_waitcnt lgkmcnt(0)" ::: "memory");                        \
    __builtin_amdgcn_sched_barrier(0);                                        \
    __builtin_amdgcn_s_setprio(1); } while (0)

  // prologue: tiles 0 and 1; vmcnt(6) drains tile0 (A0+B0), leaves A1+B1 in flight
  STA(0); STB(0); STA(1); STB(1);
  asm volatile("s_waitcnt vmcnt(6)" ::: "memory");
  __builtin_amdgcn_s_barrier();

  for (int u = 0; u < NT; ++u) {
    // P1: m-half 0
    LDA(u, 0); LDB(u);
    if (u + 2 < NT) STA(u + 2);
    PH_BEGIN(); MM(0);
    __builtin_amdgcn_s_setprio(0);
    __builtin_amdgcn_s_barrier();
    // P2: m-half 1
    LDA(u, 1);
    if (u + 2 < NT) STB(u + 2);
    PH_BEGIN(); MM(1);
    __builtin_amdgcn_s_setprio(0);
    if (u + 2 < NT) { asm volatile("s_waitcnt vmcnt(6)" ::: "memory"); }
    else if (u + 1 < NT) { asm volatile("s_waitcnt vmcnt(0)" ::: "memory"); }
    __builtin_amdgcn_s_barrier();
  }
#undef PH_BEGIN

  #pragma unroll
  for (int M = 0; M < 8; ++M)
    #pragma unroll
    for (int n = 0; n < 2; ++n)
      #pragma unroll
      for (int j = 0; j < 4; ++j) {
        long r = arow + wr * 128 + M * 16 + l4 * 4 + j;
        long c = brow + wc * 32 + n * 16 + l15;
        C[r * Ndim + c] = acc[M][n][j];
      }
}

// ---------------- fused per-head LayerNorm + RoPE (+ v passthrough convert) ----------------
__global__ __launch_bounds__(256) void ln_rope_kernel(
    const float* __restrict__ qkv, const int* __restrict__ pos,
    const float* __restrict__ qw, const float* __restrict__ qb2,
    const float* __restrict__ kw, const float* __restrict__ kb2,
    u16* __restrict__ qo, u16* __restrict__ ko, u16* __restrict__ vo, int T) {
  const int hh = blockIdx.x;
  const int t = blockIdx.y * 4 + (threadIdx.x >> 6);
  const int lane = threadIdx.x & 63;
  const float* src = qkv + (size_t)t * 12288 + hh * 128;
  float x1 = src[lane], x2 = src[lane + 64];
  if (hh >= 64) {
    u16* dst = vo + ((size_t)(hh - 64) * T + t) * 128;
    dst[lane] = f2bf(x1); dst[lane + 64] = f2bf(x2);
    return;
  }
  float s = x1 + x2;
  #pragma unroll
  for (int off = 32; off; off >>= 1) s += __shfl_xor(s, off);
  float mu = s * (1.0f / 128.0f);
  float d1 = x1 - mu, d2 = x2 - mu;
  float vs = d1 * d1 + d2 * d2;
  #pragma unroll
  for (int off = 32; off; off >>= 1) vs += __shfl_xor(vs, off);
  float rstd = rsqrtf(vs * (1.0f / 128.0f) + 1e-5f);
  bool isq = hh < 32;
  int hl = isq ? hh : hh - 32;
  const float* w = (isq ? qw : kw) + hl * 128;
  const float* b = (isq ? qb2 : kb2) + hl * 128;
  float y1 = d1 * rstd * w[lane] + b[lane];
  float y2 = d2 * rstd * w[lane + 64] + b[lane + 64];
  float p = (float)pos[t];
  float invf = exp2f((float)lane * (-13.287712379549449f / 64.0f));
  float fr = p * invf;
  float sn, cs;
  __sincosf(fr, &sn, &cs);
  float o1 = y1 * cs - y2 * sn;
  float o2 = y2 * cs + y1 * sn;
  if (isq) {
    const float sc = 0.08838834764831845f;   // 1/sqrt(128) folded into q
    o1 *= sc; o2 *= sc;
    u16* dst = qo + ((size_t)hl * T + t) * 128;
    dst[lane] = f2bf(o1); dst[lane + 64] = f2bf(o2);
  } else {
    u16* dst = ko + ((size_t)hl * T + t) * 128;
    dst[lane] = f2bf(o1); dst[lane + 64] = f2bf(o2);
  }
}

// ---------------- flash attention (causal), bf16 MFMA, online softmax ----------------
__global__ __launch_bounds__(256, 2) void flash_kernel(
    const u16* __restrict__ qb, const u16* __restrict__ kb,
    const u16* __restrict__ vb, u16* __restrict__ attn, int T) {
  __shared__ __align__(16) u16 Ks[64 * 128];
  __shared__ __align__(16) u16 Vt[128 * 64];
  __shared__ __align__(16) u16 Ps[4][32 * 64];
  const int tid = threadIdx.x;
  const int lane = tid & 63, wave = tid >> 6;
  const int l15 = lane & 15, l4 = lane >> 4;
  const int h = blockIdx.y;
  const int qbase = blockIdx.x * 128;
  const int qrow0 = qbase + wave * 32;
  const u16* Q  = qb + (size_t)h * T * 128;
  const u16* Kp = kb + (size_t)h * T * 128;
  const u16* Vp = vb + (size_t)h * T * 128;
  const int rK0 = tid >> 4, d8k = (tid & 15) * 8;

  bf16x8 qf[2][4];
  #pragma unroll
  for (int mi = 0; mi < 2; ++mi)
    #pragma unroll
    for (int kc = 0; kc < 4; ++kc)
      qf[mi][kc] = *(const bf16x8*)&Q[(size_t)(qrow0 + mi * 16 + l15) * 128 + kc * 32 + l4 * 8];

  float m_st[2][4], l_st[2][4];
  f32x4 o[2][8] = {};
  #pragma unroll
  for (int mi = 0; mi < 2; ++mi)
    #pragma unroll
    for (int j = 0; j < 4; ++j) { m_st[mi][j] = -1e30f; l_st[mi][j] = 0.0f; }

  const int ntile = (qbase + 128) / 64;
  uint4 kr[4], vr[4];
  #pragma unroll
  for (int c = 0; c < 4; ++c) {
    kr[c] = *(const uint4*)&Kp[(size_t)(rK0 + 16 * c) * 128 + d8k];
    vr[c] = *(const uint4*)&Vp[(size_t)lane * 128 + (wave + 4 * c) * 8];
  }
  for (int kt = 0; kt < ntile; ++kt) {
    const int kbase = kt * 64;
    #pragma unroll
    for (int c = 0; c < 4; ++c) {
      *(uint4*)&Ks[swz128i(rK0 + 16 * c, d8k)] = kr[c];
      const u16* pv = (const u16*)&vr[c];
      int dv = (wave + 4 * c) * 8;
      #pragma unroll
      for (int j = 0; j < 8; ++j) Vt[swz64i(dv + j, lane)] = pv[j];
    }
    __syncthreads();
    if (kt + 1 < ntile) {
      const int nb = kbase + 64;
      #pragma unroll
      for (int c = 0; c < 4; ++c) {
        kr[c] = *(const uint4*)&Kp[(size_t)(nb + rK0 + 16 * c) * 128 + d8k];
        vr[c] = *(const uint4*)&Vp[(size_t)(nb + lane) * 128 + (wave + 4 * c) * 8];
      }
    }
    if (kbase <= qrow0 + 31) {
      f32x4 s[2][4] = {};
      __builtin_amdgcn_s_setprio(1);
      #pragma unroll
      for (int kc = 0; kc < 4; ++kc)
        #pragma unroll
        for (int nj = 0; nj < 4; ++nj) {
          bf16x8 kf = *(const bf16x8*)&Ks[swz128i(nj * 16 + l15, kc * 32 + l4 * 8)];
          #pragma unroll
          for (int mi = 0; mi < 2; ++mi)
            s[mi][nj] = __builtin_amdgcn_mfma_f32_16x16x32_bf16(qf[mi][kc], kf, s[mi][nj], 0, 0, 0);
        }
      __builtin_amdgcn_s_setprio(0);
      if (kbase + 63 > qrow0) {
        #pragma unroll
        for (int mi = 0; mi < 2; ++mi)
          #pragma unroll
          for (int nj = 0; nj < 4; ++nj)
            #pragma unroll
            for (int j = 0; j < 4; ++j) {
              int r = qrow0 + mi * 16 + l4 * 4 + j;
              int cc = kbase + nj * 16 + l15;
              if (cc > r) s[mi][nj][j] = -1e30f;
            }
      }
      float vmax[2][4];
      float dmax = -1e30f;
      #pragma unroll
      for (int mi = 0; mi < 2; ++mi)
        #pragma unroll
        for (int j = 0; j < 4; ++j) {
          float v = fmaxf(fmaxf(s[mi][0][j], s[mi][1][j]), fmaxf(s[mi][2][j], s[mi][3][j]));
          #pragma unroll
          for (int off = 1; off < 16; off <<= 1) v = fmaxf(v, __shfl_xor(v, off));
          vmax[mi][j] = v;
          dmax = fmaxf(dmax, v - m_st[mi][j]);
        }
      if (!__all(dmax <= 8.0f)) {
        #pragma unroll
        for (int mi = 0; mi < 2; ++mi)
          #pragma unroll
          for (int j = 0; j < 4; ++j) {
            float mn = fmaxf(m_st[mi][j], vmax[mi][j]);
            float scl = __expf(m_st[mi][j] - mn);
            m_st[mi][j] = mn;
            l_st[mi][j] *= scl;
            #pragma unroll
            for (int nf = 0; nf < 8; ++nf) o[mi][nf][j] *= scl;
          }
      }
      #pragma unroll
      for (int mi = 0; mi < 2; ++mi) {
        float sum[4] = {0.f, 0.f, 0.f, 0.f};
        #pragma unroll
        for (int nj = 0; nj < 4; ++nj)
          #pragma unroll
          for (int j = 0; j < 4; ++j) {
            float p = __expf(s[mi][nj][j] - m_st[mi][j]);
            s[mi][nj][j] = p;
            sum[j] += p;
          }
        #pragma unroll
        for (int j = 0; j < 4; ++j) {
          #pragma unroll
          for (int off = 1; off < 16; off <<= 1) sum[j] += __shfl_xor(sum[j], off);
          l_st[mi][j] += sum[j];
        }
        #pragma unroll
        for (int nj = 0; nj < 4; ++nj)
          #pragma unroll
          for (int j = 0; j < 4; ++j)
            Ps[wave][swz64i(mi * 16 + l4 * 4 + j, nj * 16 + l15)] = f2bf(s[mi][nj][j]);
      }
      asm volatile("s_waitcnt lgkmcnt(0)" ::: "memory");
      __builtin_amdgcn_sched_barrier(0);
      __builtin_amdgcn_s_setprio(1);
      #pragma unroll
      for (int mi = 0; mi < 2; ++mi)
        #pragma unroll
        for (int kc = 0; kc < 2; ++kc) {
          bf16x8 pf = *(const bf16x8*)&Ps[wave][swz64i(mi * 16 + l15, kc * 32 + l4 * 8)];
          #pragma unroll
          for (int nf = 0; nf < 8; ++nf) {
            bf16x8 vf = *(const bf16x8*)&Vt[swz64i(nf * 16 + l15, kc * 32 + l4 * 8)];
            o[mi][nf] = __builtin_amdgcn_mfma_f32_16x16x32_bf16(pf, vf, o[mi][nf], 0, 0, 0);
          }
        }
      __builtin_amdgcn_s_setprio(0);
    }
    __syncthreads();
  }
  #pragma unroll
  for (int mi = 0; mi < 2; ++mi) {
    float rl[4];
    #pragma unroll
    for (int j = 0; j < 4; ++j) rl[j] = 1.0f / l_st[mi][j];
    #pragma unroll
    for (int nf = 0; nf < 8; ++nf)
      #pragma unroll
      for (int j = 0; j < 4; ++j) {
        int r = qrow0 + mi * 16 + l4 * 4 + j;
        int cc = h * 128 + nf * 16 + l15;
        attn[(size_t)r * 4096 + cc] = f2bf(o[mi][nf][j] * rl[j]);
      }
  }
}

// ---------------- launch ----------------
extern "C" void kernel_launch(void* const* d_in, const int* in_sizes, int n_in,
                              void* d_out, int out_size, void* d_ws, size_t ws_size,
                              hipStream_t stream) {
  const int* positions = (const int*)d_in[0];
  const float* hidden  = (const float*)d_in[1];
  const float* w_qkv   = (const float*)d_in[2];
  const float* w_o     = (const float*)d_in[3];
  const float* qnw     = (const float*)d_in[4];
  const float* qnb     = (const float*)d_in[5];
  const float* knw     = (const float*)d_in[6];
  const float* knb     = (const float*)d_in[7];
  float* out = (float*)d_out;

  const int T = in_sizes[0];           // 2048
  const int HID = 4096, NQKV = 12288, H = 32;

  char* ws = (char*)d_ws;
  u16* hid_bf  = (u16*)ws;
  u16* wreg    = (u16*)(ws + (size_t)T * HID * 2);
  float* qkv_f = (float*)(ws + (size_t)T * HID * 2 + (size_t)NQKV * HID * 2);

  u16* q_bf  = wreg;                                 // [H][T][128]
  u16* k_bf  = q_bf + (size_t)H * T * 128;           // [H][T][128]
  u16* v_bf  = k_bf + (size_t)H * T * 128;           // [H][T][128]
  u16* at_bf = v_bf + (size_t)H * T * 128;           // [T][H*128]
  u16* wo_bf = at_bf + (size_t)T * 4096;             // [4096][4096]

  hipFuncSetAttribute(reinterpret_cast<const void*>(&gemm256),
                      hipFuncAttributeMaxDynamicSharedMemorySize, 131072);

  cvt_bf16_kernel<<<2048, 256, 0, stream>>>(hidden, hid_bf, (long)T * HID / 4);
  cvt_bf16_kernel<<<4096, 256, 0, stream>>>(w_qkv, wreg, (long)NQKV * HID / 4);
  gemm256<<<dim3(NQKV / 128, T / 256), 512, 131072, stream>>>(hid_bf, wreg, qkv_f, NQKV, HID);
  ln_rope_kernel<<<dim3(96, T / 4), 256, 0, stream>>>(qkv_f, positions, qnw, qnb, knw, knb,
                                                      q_bf, k_bf, v_bf, T);
  cvt_bf16_kernel<<<2048, 256, 0, stream>>>(w_o, wo_bf, (long)HID * HID / 4);
  flash_kernel<<<dim3(T / 128, H), 256, 0, stream>>>(q_bf, k_bf, v_bf, at_bf, T);
  gemm256<<<dim3(HID / 128, T / 256), 512, 131072, stream>>>(at_bf, wo_bf, out, HID, HID);
}